// Round 4
// baseline (238.000 us; speedup 1.0000x reference)
//
#include <hip/hip_runtime.h>
#include <math.h>

#define LEAKY 0.2f
__device__ __forceinline__ float lrelu(float x){ return x >= 0.0f ? x : LEAKY*x; }

__device__ __forceinline__ unsigned short f2bf(float x){
    union { float f; unsigned u; } v; v.f = x;
    unsigned r = v.u + 0x7FFFu + ((v.u >> 16) & 1u);
    return (unsigned short)(r >> 16);
}
__device__ __forceinline__ unsigned pack2(float a, float b){
    return (unsigned)f2bf(a) | ((unsigned)f2bf(b) << 16);
}

typedef __attribute__((ext_vector_type(8))) short bf16x8;
typedef __attribute__((ext_vector_type(4))) float f32x4;

// ---------------------------------------------------------------------------
// Prep: blocks 0..575 transpose dec_w1 [4608,512]f32 -> dw1T [512][4608]bf16;
// block 576 builds w2T[branch][co 32][kp 27][ci 16] bf16 for the voxel convs.
// ---------------------------------------------------------------------------
__global__ __launch_bounds__(256) void k_prep(
    const float* __restrict__ dw1,
    const float* __restrict__ gvw2, const float* __restrict__ fvw2,
    unsigned short* __restrict__ dw1T, unsigned short* __restrict__ w2T)
{
    int blk = blockIdx.x, t = threadIdx.x;
    if (blk == 576) {
        for (int e = t; e < 27648; e += 256) {
            int branch = e / 13824, r = e - branch*13824;
            int co = r / 432, r2 = r - co*432;
            int kp = r2 >> 4, ci = r2 & 15;
            const float* src = branch ? fvw2 : gvw2;
            w2T[e] = f2bf(src[(kp*16 + ci)*32 + co]);
        }
        return;
    }
    __shared__ float s[64*65];
    int kt = blk % 72, nt = blk / 72;
    int k0 = kt*64, n0 = nt*64;
#pragma unroll
    for (int p = 0; p < 4; ++p) {
        int row = p*16 + (t >> 4);
        int col = (t & 15) * 4;
        float4 v = *(const float4*)(dw1 + (size_t)(k0 + row)*512 + n0 + col);
        s[row*65 + col]   = v.x; s[row*65 + col+1] = v.y;
        s[row*65 + col+2] = v.z; s[row*65 + col+3] = v.w;
    }
    __syncthreads();
    int nr = t >> 2, kseg = (t & 3) * 16;
    unsigned d[8];
#pragma unroll
    for (int i = 0; i < 8; ++i)
        d[i] = pack2(s[(kseg + 2*i)*65 + nr], s[(kseg + 2*i + 1)*65 + nr]);
    unsigned short* dst = dw1T + (size_t)(n0 + nr)*4608 + k0 + kseg;
    *(uint4*)dst       = make_uint4(d[0], d[1], d[2], d[3]);
    *(uint4*)(dst + 8) = make_uint4(d[4], d[5], d[6], d[7]);
}

// ---------------------------------------------------------------------------
// Voxel branch: conv3d s2 (1->16) + lrelu + conv3d s2 (16->32) + lrelu, MFMA.
// grid 256 = 2 branches x 128 batches, block 256 (4 waves). LDS 43 KB.
// ---------------------------------------------------------------------------
__global__ __launch_bounds__(256) void k_voxel(
    const float* __restrict__ pcv, const float* __restrict__ vox,
    const float* __restrict__ gvw1, const float* __restrict__ gvb1,
    const float* __restrict__ gvb2,
    const float* __restrict__ fvw1, const float* __restrict__ fvb1,
    const float* __restrict__ fvb2,
    const unsigned short* __restrict__ w2T,
    unsigned short* __restrict__ featb)
{
    __shared__ float s_in[4913];                 // [17][17][17] zero-padded
    __shared__ unsigned short mid[729*16];       // [9][9][9][16ci] zero-padded

    int blk = blockIdx.x, t = threadIdx.x;
    int w = t >> 6, l = t & 63;
    int branch = blk >> 7, b = blk & 127;
    const float* in = (branch ? vox : pcv) + (size_t)b*4096;
    const float* w1 = branch ? fvw1 : gvw1;
    const float* b1 = branch ? fvb1 : gvb1;
    const float* b2 = branch ? fvb2 : gvb2;
    const unsigned short* w2t = w2T + branch*13824;

    // P0: zero pad-cube + zero mid
    for (int i = t; i < 4913; i += 256) s_in[i] = 0.f;
    for (int i = t; i < 5832; i += 256) ((unsigned*)mid)[i] = 0u;
    __syncthreads();
    // P1: fill interior
    for (int i = t; i < 4096; i += 256) {
        int id = i >> 8, ih = (i >> 4) & 15, iw = i & 15;
        s_in[id*289 + ih*17 + iw] = in[i];
    }
    __syncthreads();

    // P2: conv1 MFMA [512 sp x 32k] @ [32k x 16co]; A built per-lane from s_in
    {
        int co = l & 15, q = l >> 4;
        bf16x8 Bf;
        int toff[8];
#pragma unroll
        for (int j = 0; j < 8; ++j) {
            int k = q*8 + j;
            float wv = (k < 27) ? w1[k*16 + co] : 0.f;
            Bf[j] = (short)f2bf(wv);
            if (k < 27) {
                int kd = k / 9, kh = (k / 3) % 3, kw = k % 3;
                toff[j] = kd*289 + kh*17 + kw;
            } else toff[j] = -1;
        }
        float bias = b1[co];
#pragma unroll
        for (int mi8 = 0; mi8 < 8; ++mi8) {
            int sp = (w*8 + mi8)*16 + (l & 15);
            int base = (sp >> 6)*578 + (((sp >> 3) & 7))*34 + (sp & 7)*2;
            unsigned av[4];
#pragma unroll
            for (int jj = 0; jj < 4; ++jj) {
                float e0 = (toff[2*jj]   >= 0) ? s_in[base + toff[2*jj]]   : 0.f;
                float e1 = (toff[2*jj+1] >= 0) ? s_in[base + toff[2*jj+1]] : 0.f;
                av[jj] = pack2(e0, e1);
            }
            bf16x8 Af;
            *(uint4*)&Af = make_uint4(av[0], av[1], av[2], av[3]);
            f32x4 acc = {0.f,0.f,0.f,0.f};
            acc = __builtin_amdgcn_mfma_f32_16x16x32_bf16(Af, Bf, acc, 0, 0, 0);
#pragma unroll
            for (int r = 0; r < 4; ++r) {
                int osp = (w*8 + mi8)*16 + q*4 + r;
                int od = osp >> 6, oh = (osp >> 3) & 7, ow = osp & 7;
                mid[(od*81 + oh*9 + ow)*16 + co] = f2bf(lrelu(acc[r] + bias));
            }
        }
    }
    __syncthreads();

    // P3: conv2 MFMA [64 sp x 432k] @ [432k x 32co], kp-pairs (K=32/step)
    {
        int nw = w & 1, mbase = (w >> 1) * 2;
        int co = nw*16 + (l & 15);
        int q = l >> 4;
        int q2 = q >> 1, ci0 = (q & 1)*8;
        int sp0 = mbase*16 + (l & 15);
        int sp1 = sp0 + 16;
        int s0 = ((sp0 >> 4)*2)*81 + (((sp0 >> 2) & 3)*2)*9 + (sp0 & 3)*2;
        int s1 = ((sp1 >> 4)*2)*81 + (((sp1 >> 2) & 3)*2)*9 + (sp1 & 3)*2;
        f32x4 acc0 = {0.f,0.f,0.f,0.f}, acc1 = {0.f,0.f,0.f,0.f};
#pragma unroll
        for (int ks = 0; ks < 14; ++ks) {
            int kp = 2*ks + q2;
            bool ok = (kp < 27);
            int kpc = ok ? kp : 0;
            int kpoff = (kpc/9)*81 + ((kpc/3)%3)*9 + (kpc%3);
            bf16x8 A0 = *(const bf16x8*)(mid + (s0 + kpoff)*16 + ci0);
            bf16x8 A1 = *(const bf16x8*)(mid + (s1 + kpoff)*16 + ci0);
            bf16x8 Bf = *(const bf16x8*)(w2t + (co*27 + kpc)*16 + ci0);
            if (!ok) { A0 = bf16x8{0,0,0,0,0,0,0,0}; A1 = bf16x8{0,0,0,0,0,0,0,0}; }
            acc0 = __builtin_amdgcn_mfma_f32_16x16x32_bf16(A0, Bf, acc0, 0, 0, 0);
            acc1 = __builtin_amdgcn_mfma_f32_16x16x32_bf16(A1, Bf, acc1, 0, 0, 0);
        }
        float bias = b2[co];
        unsigned short* o = featb + (size_t)b*4608 + (branch ? 2560 : 0);
#pragma unroll
        for (int r = 0; r < 4; ++r) {
            int spa = mbase*16 + q*4 + r;
            o[co*64 + spa]      = f2bf(lrelu(acc0[r] + bias));
            o[co*64 + spa + 16] = f2bf(lrelu(acc1[r] + bias));
        }
    }
}

// ---------------------------------------------------------------------------
// Local encoder (bf16 MFMA): grid 128 (1/batch), block 256.
// ---------------------------------------------------------------------------
__global__ __launch_bounds__(256) void k_local(
    const float* __restrict__ lpc,
    const float* __restrict__ lw1, const float* __restrict__ lb1,
    const float* __restrict__ lw2, const float* __restrict__ lb2,
    unsigned short* __restrict__ featb)
{
    __shared__ __align__(16) unsigned char lds[32768];
    int b = blockIdx.x, t = threadIdx.x;
    int w = t >> 6, l = t & 63;

#pragma unroll
    for (int q = 0; q < 8; ++q) {
        float f0 = lw2[(q*8+0)*256 + t], f1 = lw2[(q*8+1)*256 + t];
        float f2 = lw2[(q*8+2)*256 + t], f3 = lw2[(q*8+3)*256 + t];
        float f4 = lw2[(q*8+4)*256 + t], f5 = lw2[(q*8+5)*256 + t];
        float f6 = lw2[(q*8+6)*256 + t], f7 = lw2[(q*8+7)*256 + t];
        uint4 u = make_uint4(pack2(f0,f1), pack2(f2,f3), pack2(f4,f5), pack2(f6,f7));
        *(uint4*)(lds + t*128 + ((q ^ (t & 7)) * 16)) = u;
    }
    __syncthreads();

    bf16x8 Bf[4][2];
#pragma unroll
    for (int c4 = 0; c4 < 4; ++c4) {
#pragma unroll
        for (int ks = 0; ks < 2; ++ks) {
            int c = w*64 + c4*16 + (l & 15);
            int chunk = ks*4 + (l >> 4);
            Bf[c4][ks] = *(const bf16x8*)(lds + c*128 + ((chunk ^ (c & 7)) * 16));
        }
    }
    __syncthreads();

    float vmax[4] = {-INFINITY, -INFINITY, -INFINITY, -INFINITY};
    const float* pcb = lpc + (size_t)b*1024*3;

    for (int p = 0; p < 4; ++p) {
        {
            const float* pp = pcb + (p*256 + t)*3;
            float x = pp[0], y = pp[1], z = pp[2];
#pragma unroll
            for (int q = 0; q < 8; ++q) {
                float hv[8];
#pragma unroll
                for (int i = 0; i < 8; ++i) {
                    int k = q*8 + i;
                    hv[i] = lrelu(fmaf(x, lw1[k], fmaf(y, lw1[64+k], fmaf(z, lw1[128+k], lb1[k]))));
                }
                uint4 u = make_uint4(pack2(hv[0],hv[1]), pack2(hv[2],hv[3]),
                                     pack2(hv[4],hv[5]), pack2(hv[6],hv[7]));
                *(uint4*)(lds + t*128 + ((q ^ (t & 7)) * 16)) = u;
            }
        }
        __syncthreads();
#pragma unroll 4
        for (int g = 0; g < 16; ++g) {
            int row = g*16 + (l & 15);
            bf16x8 A0 = *(const bf16x8*)(lds + row*128 + ((((l>>4))     ^ (row & 7)) * 16));
            bf16x8 A1 = *(const bf16x8*)(lds + row*128 + (((4 + (l>>4)) ^ (row & 7)) * 16));
#pragma unroll
            for (int c4 = 0; c4 < 4; ++c4) {
                f32x4 acc = {0.f, 0.f, 0.f, 0.f};
                acc = __builtin_amdgcn_mfma_f32_16x16x32_bf16(A0, Bf[c4][0], acc, 0, 0, 0);
                acc = __builtin_amdgcn_mfma_f32_16x16x32_bf16(A1, Bf[c4][1], acc, 0, 0, 0);
                vmax[c4] = fmaxf(vmax[c4],
                           fmaxf(fmaxf(acc[0], acc[1]), fmaxf(acc[2], acc[3])));
            }
        }
        __syncthreads();
    }
#pragma unroll
    for (int c4 = 0; c4 < 4; ++c4) {
        vmax[c4] = fmaxf(vmax[c4], __shfl_xor(vmax[c4], 16, 64));
        vmax[c4] = fmaxf(vmax[c4], __shfl_xor(vmax[c4], 32, 64));
    }
    if (l < 16) {
#pragma unroll
        for (int c4 = 0; c4 < 4; ++c4) {
            int c = w*64 + c4*16 + l;
            featb[(size_t)b*4608 + 2048 + c] = f2bf(lrelu(vmax[c4] + lb2[c]));
        }
    }
}

// ---------------------------------------------------------------------------
// KNN + attention + pos-embed: grid 128, block 256.
// ---------------------------------------------------------------------------
__global__ __launch_bounds__(256) void k_knn(
    const float* __restrict__ gpc, const float* __restrict__ query,
    const float* __restrict__ gw1, const float* __restrict__ gb1,
    const float* __restrict__ gw2, const float* __restrict__ gb2,
    const float* __restrict__ apw, const float* __restrict__ apb,
    const float* __restrict__ asw, const float* __restrict__ asb,
    const float* __restrict__ posw, const float* __restrict__ posb,
    const float* __restrict__ bng, const float* __restrict__ bnb,
    unsigned short* __restrict__ featb)
{
    __shared__ __align__(16) unsigned char smem[20992];
    int b = blockIdx.x, t = threadIdx.x;
    int w = t >> 6, l = t & 63;
    float* knn_pos = (float*)smem;
    int*   knn_idx = (int*)(smem + 256);
    float* sdw     = (float*)(smem + 320);
    int*   siw     = (int*)(smem + 352);
    float* h_all   = (float*)(smem + 384);
    float* hqs     = (float*)(smem + 384 + 4096);
    float* sc      = (float*)(smem + 384 + 12288);

    const float* pb = gpc + (size_t)b*4096*3;
    float qx = query[b*3+0], qy = query[b*3+1], qz = query[b*3+2];
    float sq = qx*qx + qy*qy + qz*qz;

    float d2[16];
#pragma unroll
    for (int j = 0; j < 16; ++j) {
        int n = t + 256*j;
        float px = pb[n*3+0], py = pb[n*3+1], pz = pb[n*3+2];
        float sp = px*px + py*py + pz*pz;
        d2[j] = sq + sp - 2.0f*(qx*px + qy*py + qz*pz);
    }
    int used = 0;
    for (int r = 0; r < 16; ++r) {
        float bd = INFINITY; int bi = 0x7fffffff;
#pragma unroll
        for (int j = 0; j < 16; ++j) {
            float d = (used & (1 << j)) ? INFINITY : d2[j];
            int n = t + 256*j;
            if (d < bd || (d == bd && n < bi)) { bd = d; bi = n; }
        }
#pragma unroll
        for (int off = 32; off; off >>= 1) {
            float od = __shfl_xor(bd, off, 64);
            int   oi = __shfl_xor(bi, off, 64);
            if (od < bd || (od == bd && oi < bi)) { bd = od; bi = oi; }
        }
        if (l == 0) { sdw[(r & 1)*4 + w] = bd; siw[(r & 1)*4 + w] = bi; }
        __syncthreads();
        float fd = sdw[(r & 1)*4]; int fi = siw[(r & 1)*4];
#pragma unroll
        for (int ww = 1; ww < 4; ++ww) {
            float od = sdw[(r & 1)*4 + ww]; int oi = siw[(r & 1)*4 + ww];
            if (od < fd || (od == fd && oi < fi)) { fd = od; fi = oi; }
        }
        if (t == 0) knn_idx[r] = fi;
        if ((fi & 255) == t) used |= 1 << (fi >> 8);
    }
    __syncthreads();
    if (t < 16) {
        int n = knn_idx[t];
        knn_pos[t*4+0] = qx - pb[n*3+0];
        knn_pos[t*4+1] = qy - pb[n*3+1];
        knn_pos[t*4+2] = qz - pb[n*3+2];
    }
    __syncthreads();
    {
        int r = t >> 4, kk = (t & 15) * 4;
        float ppx = qx - knn_pos[r*4+0];
        float ppy = qy - knn_pos[r*4+1];
        float ppz = qz - knn_pos[r*4+2];
        float4 hv;
        float* h4 = (float*)&hv;
#pragma unroll
        for (int i = 0; i < 4; ++i) {
            int k = kk + i;
            h4[i] = lrelu(fmaf(ppx, gw1[k], fmaf(ppy, gw1[64+k], fmaf(ppz, gw1[128+k], gb1[k]))));
        }
        *(float4*)(h_all + r*64 + kk) = hv;
    }
    __syncthreads();
    {
        int r = t >> 4, c0 = (t & 15) * 8;
        float acc[8];
#pragma unroll
        for (int i = 0; i < 8; ++i) acc[i] = gb2[c0+i];
        for (int k = 0; k < 64; ++k) {
            float hv = h_all[r*64 + k];
            float4 wv0 = *(const float4*)(gw2 + k*128 + c0);
            float4 wv1 = *(const float4*)(gw2 + k*128 + c0 + 4);
            acc[0] = fmaf(hv, wv0.x, acc[0]); acc[1] = fmaf(hv, wv0.y, acc[1]);
            acc[2] = fmaf(hv, wv0.z, acc[2]); acc[3] = fmaf(hv, wv0.w, acc[3]);
            acc[4] = fmaf(hv, wv1.x, acc[4]); acc[5] = fmaf(hv, wv1.y, acc[5]);
            acc[6] = fmaf(hv, wv1.z, acc[6]); acc[7] = fmaf(hv, wv1.w, acc[7]);
        }
        float kx = knn_pos[r*4+0], ky = knn_pos[r*4+1], kz = knn_pos[r*4+2];
#pragma unroll
        for (int i = 0; i < 8; ++i) {
            int c = c0 + i;
            float pe = fmaf(kx, apw[c], fmaf(ky, apw[128+c], fmaf(kz, apw[256+c], apb[c])));
            acc[i] = lrelu(acc[i]) + pe;
        }
        *(float4*)(hqs + r*128 + c0)     = make_float4(acc[0], acc[1], acc[2], acc[3]);
        *(float4*)(hqs + r*128 + c0 + 4) = make_float4(acc[4], acc[5], acc[6], acc[7]);
    }
    __syncthreads();
    {
        int r = t >> 4, c0 = (t & 15) * 8;
        float acc[8];
#pragma unroll
        for (int i = 0; i < 8; ++i) acc[i] = asb[c0+i];
        for (int k = 0; k < 128; ++k) {
            float hv = hqs[r*128 + k];
            float4 wv0 = *(const float4*)(asw + k*128 + c0);
            float4 wv1 = *(const float4*)(asw + k*128 + c0 + 4);
            acc[0] = fmaf(hv, wv0.x, acc[0]); acc[1] = fmaf(hv, wv0.y, acc[1]);
            acc[2] = fmaf(hv, wv0.z, acc[2]); acc[3] = fmaf(hv, wv0.w, acc[3]);
            acc[4] = fmaf(hv, wv1.x, acc[4]); acc[5] = fmaf(hv, wv1.y, acc[5]);
            acc[6] = fmaf(hv, wv1.z, acc[6]); acc[7] = fmaf(hv, wv1.w, acc[7]);
        }
        *(float4*)(sc + r*128 + c0)     = make_float4(acc[0], acc[1], acc[2], acc[3]);
        *(float4*)(sc + r*128 + c0 + 4) = make_float4(acc[4], acc[5], acc[6], acc[7]);
    }
    __syncthreads();
    if (t < 128) {
        int c = t;
        float s[16]; float mx = -INFINITY;
#pragma unroll
        for (int r = 0; r < 16; ++r) { s[r] = sc[r*128 + c]; mx = fmaxf(mx, s[r]); }
        float sum = 0.f;
#pragma unroll
        for (int r = 0; r < 16; ++r) { s[r] = expf(s[r] - mx); sum += s[r]; }
        float inv = 1.0f / sum;
        float qf = 0.f;
#pragma unroll
        for (int r = 0; r < 16; ++r) qf = fmaf(s[r]*inv, hqs[r*128 + c], qf);
        featb[(size_t)b*4608 + 2304 + c] = f2bf(qf);
        float pv = fmaf(qx, posw[c], fmaf(qy, posw[128+c], fmaf(qz, posw[256+c], posb[c])));
        pv = lrelu(fmaf(bng[c], pv, bnb[c]));
        featb[(size_t)b*4608 + 2432 + c] = f2bf(pv);
    }
}

// ---------------------------------------------------------------------------
// Decoder layer 1: LDS-free register MFMA GEMM, B from pre-transposed bf16.
// grid (18 kc, 4 mg, 8 ng), block 256.
// ---------------------------------------------------------------------------
__global__ __launch_bounds__(256) void k_dec1(
    const unsigned short* __restrict__ featb, const unsigned short* __restrict__ dw1T,
    float* __restrict__ partial)      // [18][128][512]
{
    int kc = blockIdx.x, mg = blockIdx.y, ng = blockIdx.z;
    int t = threadIdx.x, w = t >> 6, l = t & 63;
    int q = l >> 4;
    int n0 = ng*64 + w*16 + (l & 15);
    const unsigned short* brow = dw1T + (size_t)n0*4608;

    f32x4 acc[2] = {{0.f,0.f,0.f,0.f},{0.f,0.f,0.f,0.f}};
#pragma unroll
    for (int ks = 0; ks < 8; ++ks) {
        int ka = kc*256 + ks*32 + q*8;
        bf16x8 Bf = *(const bf16x8*)(brow + ka);
#pragma unroll
        for (int mi = 0; mi < 2; ++mi) {
            int row = mg*32 + mi*16 + (l & 15);
            bf16x8 Af = *(const bf16x8*)(featb + (size_t)row*4608 + ka);
            acc[mi] = __builtin_amdgcn_mfma_f32_16x16x32_bf16(Af, Bf, acc[mi], 0, 0, 0);
        }
    }
    float* pb = partial + (size_t)kc*65536;
#pragma unroll
    for (int mi = 0; mi < 2; ++mi) {
#pragma unroll
        for (int r = 0; r < 4; ++r) {
            int row = mg*32 + mi*16 + q*4 + r;
            pb[row*512 + n0] = acc[mi][r];
        }
    }
}

// ---------------------------------------------------------------------------
// Decoder tail: sum 18 K-chunk partials, +b1, lrelu, dot dec_w2, +b2.
// ---------------------------------------------------------------------------
__global__ __launch_bounds__(512) void k_dec2(
    const float* __restrict__ partial, const float* __restrict__ b1,
    const float* __restrict__ w2, const float* __restrict__ b2,
    float* __restrict__ out)
{
    int b = blockIdx.x, t = threadIdx.x;
    float acc = b1[t];
#pragma unroll
    for (int kc = 0; kc < 18; ++kc)
        acc += partial[(size_t)kc*65536 + b*512 + t];
    float v = lrelu(acc) * w2[t];
#pragma unroll
    for (int off = 32; off; off >>= 1) v += __shfl_xor(v, off, 64);
    __shared__ float red[8];
    if ((t & 63) == 0) red[t >> 6] = v;
    __syncthreads();
    if (t == 0) {
        float s_ = 0.f;
#pragma unroll
        for (int i = 0; i < 8; ++i) s_ += red[i];
        out[b] = s_ + b2[0];
    }
}

extern "C" void kernel_launch(void* const* d_in, const int* in_sizes, int n_in,
                              void* d_out, int out_size, void* d_ws, size_t ws_size,
                              hipStream_t stream)
{
    const float* pc_voxel  = (const float*)d_in[0];
    const float* global_pc = (const float*)d_in[1];
    const float* local_pc  = (const float*)d_in[2];
    const float* query     = (const float*)d_in[3];
    const float* voxel     = (const float*)d_in[4];
    const float* ge_w1 = (const float*)d_in[5];
    const float* ge_b1 = (const float*)d_in[6];
    const float* ge_w2 = (const float*)d_in[7];
    const float* ge_b2 = (const float*)d_in[8];
    // d_in[9..10] = ge_w3/ge_b3: dead (global_c unused by decoder)
    const float* le_w1 = (const float*)d_in[11];
    const float* le_b1 = (const float*)d_in[12];
    const float* le_w2 = (const float*)d_in[13];
    const float* le_b2 = (const float*)d_in[14];
    const float* pos_w = (const float*)d_in[15];
    const float* pos_b = (const float*)d_in[16];
    const float* bn_g  = (const float*)d_in[17];
    const float* bn_b  = (const float*)d_in[18];
    const float* apw   = (const float*)d_in[19];
    const float* apb   = (const float*)d_in[20];
    const float* asw   = (const float*)d_in[21];
    const float* asb   = (const float*)d_in[22];
    const float* gw1 = (const float*)d_in[23];
    const float* gb1 = (const float*)d_in[24];
    const float* gw2 = (const float*)d_in[25];
    const float* gb2 = (const float*)d_in[26];
    const float* fw1 = (const float*)d_in[27];
    const float* fb1 = (const float*)d_in[28];
    const float* fw2 = (const float*)d_in[29];
    const float* fb2 = (const float*)d_in[30];
    const float* dw1 = (const float*)d_in[31];
    const float* db1 = (const float*)d_in[32];
    const float* dw2 = (const float*)d_in[33];
    const float* db2 = (const float*)d_in[34];

    // ws layout (16B-aligned chunks)
    unsigned short* featb = (unsigned short*)d_ws;                    // 1,179,648 B
    float* partial = (float*)((char*)d_ws + 1179648);                 // 4,718,592 B
    unsigned short* dw1T = (unsigned short*)((char*)d_ws + 5898240);  // 4,718,592 B
    unsigned short* w2T  = (unsigned short*)((char*)d_ws + 10616832); //    55,296 B
    float* out = (float*)d_out;

    k_prep<<<577, 256, 0, stream>>>(dw1, gw2, fw2, dw1T, w2T);
    k_voxel<<<256, 256, 0, stream>>>(pc_voxel, voxel, gw1, gb1, gb2,
                                     fw1, fb1, fb2, w2T, featb);
    k_local<<<128, 256, 0, stream>>>(local_pc, le_w1, le_b1, le_w2, le_b2, featb);
    k_knn<<<128, 256, 0, stream>>>(global_pc, query, ge_w1, ge_b1, ge_w2, ge_b2,
                                   apw, apb, asw, asb, pos_w, pos_b, bn_g, bn_b, featb);
    k_dec1<<<dim3(18, 4, 8), 256, 0, stream>>>(featb, dw1T, partial);
    k_dec2<<<128, 512, 0, stream>>>(partial, db1, dw2, db2, out);
}

// Round 5
// 223.627 us; speedup vs baseline: 1.0643x; 1.0643x over previous
//
#include <hip/hip_runtime.h>
#include <math.h>

#define LEAKY 0.2f
__device__ __forceinline__ float lrelu(float x){ return x >= 0.0f ? x : LEAKY*x; }

__device__ __forceinline__ unsigned short f2bf(float x){
    union { float f; unsigned u; } v; v.f = x;
    unsigned r = v.u + 0x7FFFu + ((v.u >> 16) & 1u);
    return (unsigned short)(r >> 16);
}
__device__ __forceinline__ unsigned pack2(float a, float b){
    return (unsigned)f2bf(a) | ((unsigned)f2bf(b) << 16);
}

typedef __attribute__((ext_vector_type(8))) short bf16x8;
typedef __attribute__((ext_vector_type(4))) float f32x4;

// ---------------------------------------------------------------------------
// Prep: blocks 0..575 transpose dec_w1 [4608,512]f32 -> dw1T [512][4608]bf16;
// block 576 builds w2T[branch][co 32][kp 27][ci 16] bf16 for the voxel convs.
// ---------------------------------------------------------------------------
__global__ __launch_bounds__(256) void k_prep(
    const float* __restrict__ dw1,
    const float* __restrict__ gvw2, const float* __restrict__ fvw2,
    unsigned short* __restrict__ dw1T, unsigned short* __restrict__ w2T)
{
    int blk = blockIdx.x, t = threadIdx.x;
    if (blk == 576) {
        for (int e = t; e < 27648; e += 256) {
            int branch = e / 13824, r = e - branch*13824;
            int co = r / 432, r2 = r - co*432;
            int kp = r2 >> 4, ci = r2 & 15;
            const float* src = branch ? fvw2 : gvw2;
            w2T[e] = f2bf(src[(kp*16 + ci)*32 + co]);
        }
        return;
    }
    __shared__ float s[64*65];
    int kt = blk % 72, nt = blk / 72;
    int k0 = kt*64, n0 = nt*64;
#pragma unroll
    for (int p = 0; p < 4; ++p) {
        int row = p*16 + (t >> 4);
        int col = (t & 15) * 4;
        float4 v = *(const float4*)(dw1 + (size_t)(k0 + row)*512 + n0 + col);
        s[row*65 + col]   = v.x; s[row*65 + col+1] = v.y;
        s[row*65 + col+2] = v.z; s[row*65 + col+3] = v.w;
    }
    __syncthreads();
    int nr = t >> 2, kseg = (t & 3) * 16;
    unsigned d[8];
#pragma unroll
    for (int i = 0; i < 8; ++i)
        d[i] = pack2(s[(kseg + 2*i)*65 + nr], s[(kseg + 2*i + 1)*65 + nr]);
    unsigned short* dst = dw1T + (size_t)(n0 + nr)*4608 + k0 + kseg;
    *(uint4*)dst       = make_uint4(d[0], d[1], d[2], d[3]);
    *(uint4*)(dst + 8) = make_uint4(d[4], d[5], d[6], d[7]);
}

// ---------------------------------------------------------------------------
// Fused voxel (blocks 0..255) + local encoder (blocks 256..383).
// ---------------------------------------------------------------------------
__global__ __launch_bounds__(256) void k_vl(
    const float* __restrict__ pcv, const float* __restrict__ vox,
    const float* __restrict__ gvw1, const float* __restrict__ gvb1,
    const float* __restrict__ gvb2,
    const float* __restrict__ fvw1, const float* __restrict__ fvb1,
    const float* __restrict__ fvb2,
    const unsigned short* __restrict__ w2T,
    const float* __restrict__ lpc,
    const float* __restrict__ lw1, const float* __restrict__ lb1,
    const float* __restrict__ lw2, const float* __restrict__ lb2,
    unsigned short* __restrict__ featb)
{
    __shared__ __align__(16) unsigned char smem[43008];
    int blk = blockIdx.x, t = threadIdx.x;
    int w = t >> 6, l = t & 63;

    if (blk < 256) {
        // ===== VOXEL =====
        float* s_in = (float*)smem;                          // [17][17][17]
        unsigned short* mid = (unsigned short*)(smem + 19664); // [9][9][9][16]
        int branch = blk >> 7, b = blk & 127;
        const float* in = (branch ? vox : pcv) + (size_t)b*4096;
        const float* w1 = branch ? fvw1 : gvw1;
        const float* b1 = branch ? fvb1 : gvb1;
        const float* b2 = branch ? fvb2 : gvb2;
        const unsigned short* w2t = w2T + branch*13824;

        for (int i = t; i < 4913; i += 256) s_in[i] = 0.f;
        for (int i = t; i < 5832; i += 256) ((unsigned*)mid)[i] = 0u;
        __syncthreads();
        for (int i = t; i < 4096; i += 256) {
            int id = i >> 8, ih = (i >> 4) & 15, iw = i & 15;
            s_in[id*289 + ih*17 + iw] = in[i];
        }
        __syncthreads();

        { // conv1 MFMA
            int co = l & 15, q = l >> 4;
            bf16x8 Bf;
            int toff[8];
#pragma unroll
            for (int j = 0; j < 8; ++j) {
                int k = q*8 + j;
                float wv = (k < 27) ? w1[k*16 + co] : 0.f;
                Bf[j] = (short)f2bf(wv);
                if (k < 27) {
                    int kd = k / 9, kh = (k / 3) % 3, kw = k % 3;
                    toff[j] = kd*289 + kh*17 + kw;
                } else toff[j] = -1;
            }
            float bias = b1[co];
#pragma unroll
            for (int mi8 = 0; mi8 < 8; ++mi8) {
                int sp = (w*8 + mi8)*16 + (l & 15);
                int base = (sp >> 6)*578 + (((sp >> 3) & 7))*34 + (sp & 7)*2;
                unsigned av[4];
#pragma unroll
                for (int jj = 0; jj < 4; ++jj) {
                    float e0 = (toff[2*jj]   >= 0) ? s_in[base + toff[2*jj]]   : 0.f;
                    float e1 = (toff[2*jj+1] >= 0) ? s_in[base + toff[2*jj+1]] : 0.f;
                    av[jj] = pack2(e0, e1);
                }
                bf16x8 Af;
                *(uint4*)&Af = make_uint4(av[0], av[1], av[2], av[3]);
                f32x4 acc = {0.f,0.f,0.f,0.f};
                acc = __builtin_amdgcn_mfma_f32_16x16x32_bf16(Af, Bf, acc, 0, 0, 0);
#pragma unroll
                for (int r = 0; r < 4; ++r) {
                    int osp = (w*8 + mi8)*16 + q*4 + r;
                    int od = osp >> 6, oh = (osp >> 3) & 7, ow = osp & 7;
                    mid[(od*81 + oh*9 + ow)*16 + co] = f2bf(lrelu(acc[r] + bias));
                }
            }
        }
        __syncthreads();

        { // conv2 MFMA
            int nw = w & 1, mbase = (w >> 1) * 2;
            int co = nw*16 + (l & 15);
            int q = l >> 4;
            int q2 = q >> 1, ci0 = (q & 1)*8;
            int sp0 = mbase*16 + (l & 15);
            int sp1 = sp0 + 16;
            int s0 = ((sp0 >> 4)*2)*81 + (((sp0 >> 2) & 3)*2)*9 + (sp0 & 3)*2;
            int s1 = ((sp1 >> 4)*2)*81 + (((sp1 >> 2) & 3)*2)*9 + (sp1 & 3)*2;
            f32x4 acc0 = {0.f,0.f,0.f,0.f}, acc1 = {0.f,0.f,0.f,0.f};
#pragma unroll
            for (int ks = 0; ks < 14; ++ks) {
                int kp = 2*ks + q2;
                bool ok = (kp < 27);
                int kpc = ok ? kp : 0;
                int kpoff = (kpc/9)*81 + ((kpc/3)%3)*9 + (kpc%3);
                bf16x8 A0 = *(const bf16x8*)(mid + (s0 + kpoff)*16 + ci0);
                bf16x8 A1 = *(const bf16x8*)(mid + (s1 + kpoff)*16 + ci0);
                bf16x8 Bf = *(const bf16x8*)(w2t + (co*27 + kpc)*16 + ci0);
                if (!ok) { A0 = bf16x8{0,0,0,0,0,0,0,0}; A1 = bf16x8{0,0,0,0,0,0,0,0}; }
                acc0 = __builtin_amdgcn_mfma_f32_16x16x32_bf16(A0, Bf, acc0, 0, 0, 0);
                acc1 = __builtin_amdgcn_mfma_f32_16x16x32_bf16(A1, Bf, acc1, 0, 0, 0);
            }
            float bias = b2[co];
            unsigned short* o = featb + (size_t)b*4608 + (branch ? 2560 : 0);
#pragma unroll
            for (int r = 0; r < 4; ++r) {
                int spa = mbase*16 + q*4 + r;
                o[co*64 + spa]      = f2bf(lrelu(acc0[r] + bias));
                o[co*64 + spa + 16] = f2bf(lrelu(acc1[r] + bias));
            }
        }
    } else {
        // ===== LOCAL ENCODER =====
        unsigned char* lds = smem;
        int b = blk - 256;
#pragma unroll
        for (int q = 0; q < 8; ++q) {
            float f0 = lw2[(q*8+0)*256 + t], f1 = lw2[(q*8+1)*256 + t];
            float f2 = lw2[(q*8+2)*256 + t], f3 = lw2[(q*8+3)*256 + t];
            float f4 = lw2[(q*8+4)*256 + t], f5 = lw2[(q*8+5)*256 + t];
            float f6 = lw2[(q*8+6)*256 + t], f7 = lw2[(q*8+7)*256 + t];
            uint4 u = make_uint4(pack2(f0,f1), pack2(f2,f3), pack2(f4,f5), pack2(f6,f7));
            *(uint4*)(lds + t*128 + ((q ^ (t & 7)) * 16)) = u;
        }
        __syncthreads();

        bf16x8 Bf[4][2];
#pragma unroll
        for (int c4 = 0; c4 < 4; ++c4) {
#pragma unroll
            for (int ks = 0; ks < 2; ++ks) {
                int c = w*64 + c4*16 + (l & 15);
                int chunk = ks*4 + (l >> 4);
                Bf[c4][ks] = *(const bf16x8*)(lds + c*128 + ((chunk ^ (c & 7)) * 16));
            }
        }
        __syncthreads();

        float vmax[4] = {-INFINITY, -INFINITY, -INFINITY, -INFINITY};
        const float* pcb = lpc + (size_t)b*1024*3;

        for (int p = 0; p < 4; ++p) {
            {
                const float* pp = pcb + (p*256 + t)*3;
                float x = pp[0], y = pp[1], z = pp[2];
#pragma unroll
                for (int q = 0; q < 8; ++q) {
                    float hv[8];
#pragma unroll
                    for (int i = 0; i < 8; ++i) {
                        int k = q*8 + i;
                        hv[i] = lrelu(fmaf(x, lw1[k], fmaf(y, lw1[64+k], fmaf(z, lw1[128+k], lb1[k]))));
                    }
                    uint4 u = make_uint4(pack2(hv[0],hv[1]), pack2(hv[2],hv[3]),
                                         pack2(hv[4],hv[5]), pack2(hv[6],hv[7]));
                    *(uint4*)(lds + t*128 + ((q ^ (t & 7)) * 16)) = u;
                }
            }
            __syncthreads();
#pragma unroll 4
            for (int g = 0; g < 16; ++g) {
                int row = g*16 + (l & 15);
                bf16x8 A0 = *(const bf16x8*)(lds + row*128 + ((((l>>4))     ^ (row & 7)) * 16));
                bf16x8 A1 = *(const bf16x8*)(lds + row*128 + (((4 + (l>>4)) ^ (row & 7)) * 16));
#pragma unroll
                for (int c4 = 0; c4 < 4; ++c4) {
                    f32x4 acc = {0.f, 0.f, 0.f, 0.f};
                    acc = __builtin_amdgcn_mfma_f32_16x16x32_bf16(A0, Bf[c4][0], acc, 0, 0, 0);
                    acc = __builtin_amdgcn_mfma_f32_16x16x32_bf16(A1, Bf[c4][1], acc, 0, 0, 0);
                    vmax[c4] = fmaxf(vmax[c4],
                               fmaxf(fmaxf(acc[0], acc[1]), fmaxf(acc[2], acc[3])));
                }
            }
            __syncthreads();
        }
#pragma unroll
        for (int c4 = 0; c4 < 4; ++c4) {
            vmax[c4] = fmaxf(vmax[c4], __shfl_xor(vmax[c4], 16, 64));
            vmax[c4] = fmaxf(vmax[c4], __shfl_xor(vmax[c4], 32, 64));
        }
        if (l < 16) {
#pragma unroll
            for (int c4 = 0; c4 < 4; ++c4) {
                int c = w*64 + c4*16 + l;
                featb[(size_t)b*4608 + 2048 + c] = f2bf(lrelu(vmax[c4] + lb2[c]));
            }
        }
    }
}

// ---------------------------------------------------------------------------
// KNN + attention, latency-optimized. Grid 128, block 256 (4 waves).
// Points staged in LDS; selection = wave-local shuffle rounds + 1 merge;
// only 3 barriers on the selection path. (256,1) bounds -> big VGPR budget.
// ---------------------------------------------------------------------------
__global__ __launch_bounds__(256, 1) void k_knn(
    const float* __restrict__ gpc, const float* __restrict__ query,
    const float* __restrict__ gw1, const float* __restrict__ gb1,
    const float* __restrict__ gw2, const float* __restrict__ gb2,
    const float* __restrict__ apw, const float* __restrict__ apb,
    const float* __restrict__ asw, const float* __restrict__ asb,
    const float* __restrict__ posw, const float* __restrict__ posb,
    const float* __restrict__ bng, const float* __restrict__ bnb,
    unsigned short* __restrict__ featb)
{
    __shared__ __align__(16) unsigned char smem[50176];
    float* pts     = (float*)smem;            // [4096*3] f32 (dies after extraction)
    float* h_all   = (float*)smem;            // overlay: [16][64]
    float* hqs     = (float*)(smem + 4096);   // overlay: [16][128]
    float* sc      = (float*)(smem + 12288);  // overlay: [16][128]
    float* knn_pos = (float*)(smem + 49152);  // [16][4]
    float* sd      = (float*)(smem + 49408);  // [64]
    int*   sn      = (int*)(smem + 49664);    // [64]

    int b = blockIdx.x, t = threadIdx.x;
    int w = t >> 6, l = t & 63;
    const float* pb = gpc + (size_t)b*4096*3;

    // stage points (48 KB, coalesced)
#pragma unroll
    for (int i = 0; i < 12; ++i)
        ((uint4*)pts)[t + 256*i] = ((const uint4*)pb)[t + 256*i];

    float qx = query[b*3+0], qy = query[b*3+1], qz = query[b*3+2];
    float sq = qx*qx + qy*qy + qz*qz;
    __syncthreads();

    // distances (from LDS, all loads batched)
    float px[16], py[16], pz[16], d2[16];
#pragma unroll
    for (int j = 0; j < 16; ++j) {
        int n = t + 256*j;
        px[j] = pts[n*3+0]; py[j] = pts[n*3+1]; pz[j] = pts[n*3+2];
    }
#pragma unroll
    for (int j = 0; j < 16; ++j) {
        float sp = px[j]*px[j] + py[j]*py[j] + pz[j]*pz[j];
        d2[j] = sq + sp - 2.0f*(qx*px[j] + qy*py[j] + qz*pz[j]);
    }

    // wave-local top-16 (shuffle-only, no barriers)
    unsigned avail = 0xFFFFu;
    float myd = 0.f; int myn = 0;
    for (int r = 0; r < 16; ++r) {
        float bd = INFINITY; int bj = -1;
#pragma unroll
        for (int j = 0; j < 16; ++j) {
            float d = (avail & (1u << j)) ? d2[j] : INFINITY;
            if (d < bd) { bd = d; bj = j; }
        }
        int bn = (bj >= 0) ? (t + 256*bj) : 0x7fffffff;
        float wd = bd; int wn = bn;
#pragma unroll
        for (int off = 32; off; off >>= 1) {
            float od = __shfl_xor(wd, off, 64);
            int   on = __shfl_xor(wn, off, 64);
            if (od < wd || (od == wd && on < wn)) { wd = od; wn = on; }
        }
        if (wn == bn) avail &= ~(1u << bj);   // winner lane retires its candidate
        if (l == r) { myd = wd; myn = wn; }
    }
    if (l < 16) { sd[w*16 + l] = myd; sn[w*16 + l] = myn; }
    __syncthreads();

    // wave-0 merge of 64 candidates -> top-16, extract knn_pos
    if (w == 0) {
        float d = sd[l]; int n = sn[l];
        int win_n = 0;
        for (int r = 0; r < 16; ++r) {
            float wd = d; int wn = n;
#pragma unroll
            for (int off = 32; off; off >>= 1) {
                float od = __shfl_xor(wd, off, 64);
                int   on = __shfl_xor(wn, off, 64);
                if (od < wd || (od == wd && on < wn)) { wd = od; wn = on; }
            }
            if (n == wn) d = INFINITY;        // n unique -> exact removal
            if (l == r) win_n = wn;
        }
        if (l < 16) {
            knn_pos[l*4+0] = qx - pts[win_n*3+0];
            knn_pos[l*4+1] = qy - pts[win_n*3+1];
            knn_pos[l*4+2] = qz - pts[win_n*3+2];
        }
    }
    __syncthreads();   // pts dead; attention buffers overlay

    { // h for 16 neighbors: (r = t>>4, 4 channels each)
        int r = t >> 4, kk = (t & 15) * 4;
        float ppx = qx - knn_pos[r*4+0];
        float ppy = qy - knn_pos[r*4+1];
        float ppz = qz - knn_pos[r*4+2];
#pragma unroll
        for (int i = 0; i < 4; ++i) {
            int k = kk + i;
            h_all[r*64 + k] = lrelu(fmaf(ppx, gw1[k],
                               fmaf(ppy, gw1[64+k], fmaf(ppz, gw1[128+k], gb1[k]))));
        }
    }
    __syncthreads();
    { // hq[r][c] = lrelu(h@gw2 + gb2) + (knn_pos@apw + apb)
        int r = t >> 4, c0 = (t & 15) * 8;
        float acc[8];
#pragma unroll
        for (int i = 0; i < 8; ++i) acc[i] = gb2[c0+i];
#pragma unroll 8
        for (int k = 0; k < 64; ++k) {
            float hv = h_all[r*64 + k];
            float4 wv0 = *(const float4*)(gw2 + k*128 + c0);
            float4 wv1 = *(const float4*)(gw2 + k*128 + c0 + 4);
            acc[0] = fmaf(hv, wv0.x, acc[0]); acc[1] = fmaf(hv, wv0.y, acc[1]);
            acc[2] = fmaf(hv, wv0.z, acc[2]); acc[3] = fmaf(hv, wv0.w, acc[3]);
            acc[4] = fmaf(hv, wv1.x, acc[4]); acc[5] = fmaf(hv, wv1.y, acc[5]);
            acc[6] = fmaf(hv, wv1.z, acc[6]); acc[7] = fmaf(hv, wv1.w, acc[7]);
        }
        float kx = knn_pos[r*4+0], ky = knn_pos[r*4+1], kz = knn_pos[r*4+2];
#pragma unroll
        for (int i = 0; i < 8; ++i) {
            int c = c0 + i;
            float pe = fmaf(kx, apw[c], fmaf(ky, apw[128+c], fmaf(kz, apw[256+c], apb[c])));
            acc[i] = lrelu(acc[i]) + pe;
        }
        *(float4*)(hqs + r*128 + c0)     = make_float4(acc[0], acc[1], acc[2], acc[3]);
        *(float4*)(hqs + r*128 + c0 + 4) = make_float4(acc[4], acc[5], acc[6], acc[7]);
    }
    __syncthreads();
    { // scores
        int r = t >> 4, c0 = (t & 15) * 8;
        float acc[8];
#pragma unroll
        for (int i = 0; i < 8; ++i) acc[i] = asb[c0+i];
#pragma unroll 8
        for (int k = 0; k < 128; ++k) {
            float hv = hqs[r*128 + k];
            float4 wv0 = *(const float4*)(asw + k*128 + c0);
            float4 wv1 = *(const float4*)(asw + k*128 + c0 + 4);
            acc[0] = fmaf(hv, wv0.x, acc[0]); acc[1] = fmaf(hv, wv0.y, acc[1]);
            acc[2] = fmaf(hv, wv0.z, acc[2]); acc[3] = fmaf(hv, wv0.w, acc[3]);
            acc[4] = fmaf(hv, wv1.x, acc[4]); acc[5] = fmaf(hv, wv1.y, acc[5]);
            acc[6] = fmaf(hv, wv1.z, acc[6]); acc[7] = fmaf(hv, wv1.w, acc[7]);
        }
        *(float4*)(sc + r*128 + c0)     = make_float4(acc[0], acc[1], acc[2], acc[3]);
        *(float4*)(sc + r*128 + c0 + 4) = make_float4(acc[4], acc[5], acc[6], acc[7]);
    }
    __syncthreads();
    if (t < 128) { // softmax + weighted sum (waves 0-1)
        int c = t;
        float s[16]; float mx = -INFINITY;
#pragma unroll
        for (int r = 0; r < 16; ++r) { s[r] = sc[r*128 + c]; mx = fmaxf(mx, s[r]); }
        float sum = 0.f;
#pragma unroll
        for (int r = 0; r < 16; ++r) { s[r] = expf(s[r] - mx); sum += s[r]; }
        float inv = 1.0f / sum;
        float qf = 0.f;
#pragma unroll
        for (int r = 0; r < 16; ++r) qf = fmaf(s[r]*inv, hqs[r*128 + c], qf);
        featb[(size_t)b*4608 + 2304 + c] = f2bf(qf);
    } else {       // position embedding (waves 2-3, concurrent)
        int c = t - 128;
        float pv = fmaf(qx, posw[c], fmaf(qy, posw[128+c], fmaf(qz, posw[256+c], posb[c])));
        pv = lrelu(fmaf(bng[c], pv, bnb[c]));
        featb[(size_t)b*4608 + 2432 + c] = f2bf(pv);
    }
}

// ---------------------------------------------------------------------------
// Decoder layer 1: LDS-free register MFMA GEMM, B pre-transposed bf16.
// ---------------------------------------------------------------------------
__global__ __launch_bounds__(256) void k_dec1(
    const unsigned short* __restrict__ featb, const unsigned short* __restrict__ dw1T,
    float* __restrict__ partial)      // [18][128][512]
{
    int kc = blockIdx.x, mg = blockIdx.y, ng = blockIdx.z;
    int t = threadIdx.x, w = t >> 6, l = t & 63;
    int q = l >> 4;
    int n0 = ng*64 + w*16 + (l & 15);
    const unsigned short* brow = dw1T + (size_t)n0*4608;

    f32x4 acc[2] = {{0.f,0.f,0.f,0.f},{0.f,0.f,0.f,0.f}};
#pragma unroll
    for (int ks = 0; ks < 8; ++ks) {
        int ka = kc*256 + ks*32 + q*8;
        bf16x8 Bf = *(const bf16x8*)(brow + ka);
#pragma unroll
        for (int mi = 0; mi < 2; ++mi) {
            int row = mg*32 + mi*16 + (l & 15);
            bf16x8 Af = *(const bf16x8*)(featb + (size_t)row*4608 + ka);
            acc[mi] = __builtin_amdgcn_mfma_f32_16x16x32_bf16(Af, Bf, acc[mi], 0, 0, 0);
        }
    }
    float* pb = partial + (size_t)kc*65536;
#pragma unroll
    for (int mi = 0; mi < 2; ++mi) {
#pragma unroll
        for (int r = 0; r < 4; ++r) {
            int row = mg*32 + mi*16 + q*4 + r;
            pb[row*512 + n0] = acc[mi][r];
        }
    }
}

__global__ __launch_bounds__(512) void k_dec2(
    const float* __restrict__ partial, const float* __restrict__ b1,
    const float* __restrict__ w2, const float* __restrict__ b2,
    float* __restrict__ out)
{
    int b = blockIdx.x, t = threadIdx.x;
    float acc = b1[t];
#pragma unroll
    for (int kc = 0; kc < 18; ++kc)
        acc += partial[(size_t)kc*65536 + b*512 + t];
    float v = lrelu(acc) * w2[t];
#pragma unroll
    for (int off = 32; off; off >>= 1) v += __shfl_xor(v, off, 64);
    __shared__ float red[8];
    if ((t & 63) == 0) red[t >> 6] = v;
    __syncthreads();
    if (t == 0) {
        float s_ = 0.f;
#pragma unroll
        for (int i = 0; i < 8; ++i) s_ += red[i];
        out[b] = s_ + b2[0];
    }
}

extern "C" void kernel_launch(void* const* d_in, const int* in_sizes, int n_in,
                              void* d_out, int out_size, void* d_ws, size_t ws_size,
                              hipStream_t stream)
{
    const float* pc_voxel  = (const float*)d_in[0];
    const float* global_pc = (const float*)d_in[1];
    const float* local_pc  = (const float*)d_in[2];
    const float* query     = (const float*)d_in[3];
    const float* voxel     = (const float*)d_in[4];
    const float* ge_w1 = (const float*)d_in[5];
    const float* ge_b1 = (const float*)d_in[6];
    const float* ge_w2 = (const float*)d_in[7];
    const float* ge_b2 = (const float*)d_in[8];
    // d_in[9..10] = ge_w3/ge_b3: dead (global_c unused by decoder)
    const float* le_w1 = (const float*)d_in[11];
    const float* le_b1 = (const float*)d_in[12];
    const float* le_w2 = (const float*)d_in[13];
    const float* le_b2 = (const float*)d_in[14];
    const float* pos_w = (const float*)d_in[15];
    const float* pos_b = (const float*)d_in[16];
    const float* bn_g  = (const float*)d_in[17];
    const float* bn_b  = (const float*)d_in[18];
    const float* apw   = (const float*)d_in[19];
    const float* apb   = (const float*)d_in[20];
    const float* asw   = (const float*)d_in[21];
    const float* asb   = (const float*)d_in[22];
    const float* gw1 = (const float*)d_in[23];
    const float* gb1 = (const float*)d_in[24];
    const float* gw2 = (const float*)d_in[25];
    const float* gb2 = (const float*)d_in[26];
    const float* fw1 = (const float*)d_in[27];
    const float* fb1 = (const float*)d_in[28];
    const float* fw2 = (const float*)d_in[29];
    const float* fb2 = (const float*)d_in[30];
    const float* dw1 = (const float*)d_in[31];
    const float* db1 = (const float*)d_in[32];
    const float* dw2 = (const float*)d_in[33];
    const float* db2 = (const float*)d_in[34];

    unsigned short* featb = (unsigned short*)d_ws;                    // 1,179,648 B
    float* partial = (float*)((char*)d_ws + 1179648);                 // 4,718,592 B
    unsigned short* dw1T = (unsigned short*)((char*)d_ws + 5898240);  // 4,718,592 B
    unsigned short* w2T  = (unsigned short*)((char*)d_ws + 10616832); //    55,296 B
    float* out = (float*)d_out;

    k_prep<<<577, 256, 0, stream>>>(dw1, gw2, fw2, dw1T, w2T);
    k_vl<<<384, 256, 0, stream>>>(pc_voxel, voxel, gw1, gb1, gb2, fw1, fb1, fb2,
                                  w2T, local_pc, le_w1, le_b1, le_w2, le_b2, featb);
    k_knn<<<128, 256, 0, stream>>>(global_pc, query, ge_w1, ge_b1, ge_w2, ge_b2,
                                   apw, apb, asw, asb, pos_w, pos_b, bn_g, bn_b, featb);
    k_dec1<<<dim3(18, 4, 8), 256, 0, stream>>>(featb, dw1T, partial);
    k_dec2<<<128, 512, 0, stream>>>(partial, db1, dw2, db2, out);
}

// Round 6
// 218.440 us; speedup vs baseline: 1.0895x; 1.0237x over previous
//
#include <hip/hip_runtime.h>
#include <math.h>

#define LEAKY 0.2f
__device__ __forceinline__ float lrelu(float x){ return x >= 0.0f ? x : LEAKY*x; }

__device__ __forceinline__ unsigned short f2bf(float x){
    union { float f; unsigned u; } v; v.f = x;
    unsigned r = v.u + 0x7FFFu + ((v.u >> 16) & 1u);
    return (unsigned short)(r >> 16);
}
__device__ __forceinline__ unsigned pack2(float a, float b){
    return (unsigned)f2bf(a) | ((unsigned)f2bf(b) << 16);
}

typedef __attribute__((ext_vector_type(8))) short bf16x8;
typedef __attribute__((ext_vector_type(4))) float f32x4;

// ---------------------------------------------------------------------------
// Prep: blocks 0..575 transpose dec_w1 -> dw1T [512][4608] bf16;
// block 576 builds w2T[branch][co32][kp27][ci16] bf16.
// ---------------------------------------------------------------------------
__global__ __launch_bounds__(256) void k_prep(
    const float* __restrict__ dw1,
    const float* __restrict__ gvw2, const float* __restrict__ fvw2,
    unsigned short* __restrict__ dw1T, unsigned short* __restrict__ w2T)
{
    int blk = blockIdx.x, t = threadIdx.x;
    if (blk == 576) {
        for (int e = t; e < 27648; e += 256) {
            int branch = e / 13824, r = e - branch*13824;
            int co = r / 432, r2 = r - co*432;
            int kp = r2 >> 4, ci = r2 & 15;
            const float* src = branch ? fvw2 : gvw2;
            w2T[e] = f2bf(src[(kp*16 + ci)*32 + co]);
        }
        return;
    }
    __shared__ float s[64*65];
    int kt = blk % 72, nt = blk / 72;
    int k0 = kt*64, n0 = nt*64;
#pragma unroll
    for (int p = 0; p < 4; ++p) {
        int row = p*16 + (t >> 4);
        int col = (t & 15) * 4;
        float4 v = *(const float4*)(dw1 + (size_t)(k0 + row)*512 + n0 + col);
        s[row*65 + col]   = v.x; s[row*65 + col+1] = v.y;
        s[row*65 + col+2] = v.z; s[row*65 + col+3] = v.w;
    }
    __syncthreads();
    int nr = t >> 2, kseg = (t & 3) * 16;
    unsigned d[8];
#pragma unroll
    for (int i = 0; i < 8; ++i)
        d[i] = pack2(s[(kseg + 2*i)*65 + nr], s[(kseg + 2*i + 1)*65 + nr]);
    unsigned short* dst = dw1T + (size_t)(n0 + nr)*4608 + k0 + kseg;
    *(uint4*)dst       = make_uint4(d[0], d[1], d[2], d[3]);
    *(uint4*)(dst + 8) = make_uint4(d[4], d[5], d[6], d[7]);
}

// ---------------------------------------------------------------------------
// Mega: voxel (0..255) + local (256..383) + KNN-select (384..895).
// Sel: block = (batch, quarter), 1024 pts direct from global, wave-local
// top-16 via lex-(d,n) shuffle argmin, wave-0 merge -> cand[b][qt][16].
// ---------------------------------------------------------------------------
__global__ __launch_bounds__(256) void k_mega(
    const float* __restrict__ pcv, const float* __restrict__ vox,
    const float* __restrict__ gvw1, const float* __restrict__ gvb1,
    const float* __restrict__ gvb2,
    const float* __restrict__ fvw1, const float* __restrict__ fvb1,
    const float* __restrict__ fvb2,
    const unsigned short* __restrict__ w2T,
    const float* __restrict__ lpc,
    const float* __restrict__ lw1, const float* __restrict__ lb1,
    const float* __restrict__ lw2, const float* __restrict__ lb2,
    const float* __restrict__ gpc, const float* __restrict__ query,
    float* __restrict__ candd, int* __restrict__ candn,
    unsigned short* __restrict__ featb)
{
    __shared__ __align__(16) unsigned char smem[43008];
    int blk = blockIdx.x, t = threadIdx.x;
    int w = t >> 6, l = t & 63;

    if (blk < 256) {
        // ===== VOXEL =====
        float* s_in = (float*)smem;                            // [17][17][17]
        unsigned short* mid = (unsigned short*)(smem + 19664); // [9][9][9][16]
        int branch = blk >> 7, b = blk & 127;
        const float* in = (branch ? vox : pcv) + (size_t)b*4096;
        const float* w1 = branch ? fvw1 : gvw1;
        const float* b1 = branch ? fvb1 : gvb1;
        const float* b2 = branch ? fvb2 : gvb2;
        const unsigned short* w2t = w2T + branch*13824;

        for (int i = t; i < 4913; i += 256) s_in[i] = 0.f;
        for (int i = t; i < 5832; i += 256) ((unsigned*)mid)[i] = 0u;
        __syncthreads();
        for (int i = t; i < 4096; i += 256) {
            int id = i >> 8, ih = (i >> 4) & 15, iw = i & 15;
            s_in[id*289 + ih*17 + iw] = in[i];
        }
        __syncthreads();

        { // conv1 MFMA
            int co = l & 15, q = l >> 4;
            bf16x8 Bf;
            int toff[8];
#pragma unroll
            for (int j = 0; j < 8; ++j) {
                int k = q*8 + j;
                float wv = (k < 27) ? w1[k*16 + co] : 0.f;
                Bf[j] = (short)f2bf(wv);
                if (k < 27) {
                    int kd = k / 9, kh = (k / 3) % 3, kw = k % 3;
                    toff[j] = kd*289 + kh*17 + kw;
                } else toff[j] = -1;
            }
            float bias = b1[co];
#pragma unroll
            for (int mi8 = 0; mi8 < 8; ++mi8) {
                int sp = (w*8 + mi8)*16 + (l & 15);
                int base = (sp >> 6)*578 + (((sp >> 3) & 7))*34 + (sp & 7)*2;
                unsigned av[4];
#pragma unroll
                for (int jj = 0; jj < 4; ++jj) {
                    float e0 = (toff[2*jj]   >= 0) ? s_in[base + toff[2*jj]]   : 0.f;
                    float e1 = (toff[2*jj+1] >= 0) ? s_in[base + toff[2*jj+1]] : 0.f;
                    av[jj] = pack2(e0, e1);
                }
                bf16x8 Af;
                *(uint4*)&Af = make_uint4(av[0], av[1], av[2], av[3]);
                f32x4 acc = {0.f,0.f,0.f,0.f};
                acc = __builtin_amdgcn_mfma_f32_16x16x32_bf16(Af, Bf, acc, 0, 0, 0);
#pragma unroll
                for (int r = 0; r < 4; ++r) {
                    int osp = (w*8 + mi8)*16 + q*4 + r;
                    int od = osp >> 6, oh = (osp >> 3) & 7, ow = osp & 7;
                    mid[(od*81 + oh*9 + ow)*16 + co] = f2bf(lrelu(acc[r] + bias));
                }
            }
        }
        __syncthreads();

        { // conv2 MFMA
            int nw = w & 1, mbase = (w >> 1) * 2;
            int co = nw*16 + (l & 15);
            int q = l >> 4;
            int q2 = q >> 1, ci0 = (q & 1)*8;
            int sp0 = mbase*16 + (l & 15);
            int sp1 = sp0 + 16;
            int s0 = ((sp0 >> 4)*2)*81 + (((sp0 >> 2) & 3)*2)*9 + (sp0 & 3)*2;
            int s1 = ((sp1 >> 4)*2)*81 + (((sp1 >> 2) & 3)*2)*9 + (sp1 & 3)*2;
            f32x4 acc0 = {0.f,0.f,0.f,0.f}, acc1 = {0.f,0.f,0.f,0.f};
#pragma unroll
            for (int ks = 0; ks < 14; ++ks) {
                int kp = 2*ks + q2;
                bool ok = (kp < 27);
                int kpc = ok ? kp : 0;
                int kpoff = (kpc/9)*81 + ((kpc/3)%3)*9 + (kpc%3);
                bf16x8 A0 = *(const bf16x8*)(mid + (s0 + kpoff)*16 + ci0);
                bf16x8 A1 = *(const bf16x8*)(mid + (s1 + kpoff)*16 + ci0);
                bf16x8 Bf = *(const bf16x8*)(w2t + (co*27 + kpc)*16 + ci0);
                if (!ok) { A0 = bf16x8{0,0,0,0,0,0,0,0}; A1 = bf16x8{0,0,0,0,0,0,0,0}; }
                acc0 = __builtin_amdgcn_mfma_f32_16x16x32_bf16(A0, Bf, acc0, 0, 0, 0);
                acc1 = __builtin_amdgcn_mfma_f32_16x16x32_bf16(A1, Bf, acc1, 0, 0, 0);
            }
            float bias = b2[co];
            unsigned short* o = featb + (size_t)b*4608 + (branch ? 2560 : 0);
#pragma unroll
            for (int r = 0; r < 4; ++r) {
                int spa = mbase*16 + q*4 + r;
                o[co*64 + spa]      = f2bf(lrelu(acc0[r] + bias));
                o[co*64 + spa + 16] = f2bf(lrelu(acc1[r] + bias));
            }
        }
    } else if (blk < 384) {
        // ===== LOCAL ENCODER =====
        unsigned char* lds = smem;
        int b = blk - 256;
#pragma unroll
        for (int q = 0; q < 8; ++q) {
            float f0 = lw2[(q*8+0)*256 + t], f1 = lw2[(q*8+1)*256 + t];
            float f2 = lw2[(q*8+2)*256 + t], f3 = lw2[(q*8+3)*256 + t];
            float f4 = lw2[(q*8+4)*256 + t], f5 = lw2[(q*8+5)*256 + t];
            float f6 = lw2[(q*8+6)*256 + t], f7 = lw2[(q*8+7)*256 + t];
            uint4 u = make_uint4(pack2(f0,f1), pack2(f2,f3), pack2(f4,f5), pack2(f6,f7));
            *(uint4*)(lds + t*128 + ((q ^ (t & 7)) * 16)) = u;
        }
        __syncthreads();

        bf16x8 Bf[4][2];
#pragma unroll
        for (int c4 = 0; c4 < 4; ++c4) {
#pragma unroll
            for (int ks = 0; ks < 2; ++ks) {
                int c = w*64 + c4*16 + (l & 15);
                int chunk = ks*4 + (l >> 4);
                Bf[c4][ks] = *(const bf16x8*)(lds + c*128 + ((chunk ^ (c & 7)) * 16));
            }
        }
        __syncthreads();

        float vmax[4] = {-INFINITY, -INFINITY, -INFINITY, -INFINITY};
        const float* pcb = lpc + (size_t)b*1024*3;

        for (int p = 0; p < 4; ++p) {
            {
                const float* pp = pcb + (p*256 + t)*3;
                float x = pp[0], y = pp[1], z = pp[2];
#pragma unroll
                for (int q = 0; q < 8; ++q) {
                    float hv[8];
#pragma unroll
                    for (int i = 0; i < 8; ++i) {
                        int k = q*8 + i;
                        hv[i] = lrelu(fmaf(x, lw1[k], fmaf(y, lw1[64+k], fmaf(z, lw1[128+k], lb1[k]))));
                    }
                    uint4 u = make_uint4(pack2(hv[0],hv[1]), pack2(hv[2],hv[3]),
                                         pack2(hv[4],hv[5]), pack2(hv[6],hv[7]));
                    *(uint4*)(lds + t*128 + ((q ^ (t & 7)) * 16)) = u;
                }
            }
            __syncthreads();
#pragma unroll 4
            for (int g = 0; g < 16; ++g) {
                int row = g*16 + (l & 15);
                bf16x8 A0 = *(const bf16x8*)(lds + row*128 + ((((l>>4))     ^ (row & 7)) * 16));
                bf16x8 A1 = *(const bf16x8*)(lds + row*128 + (((4 + (l>>4)) ^ (row & 7)) * 16));
#pragma unroll
                for (int c4 = 0; c4 < 4; ++c4) {
                    f32x4 acc = {0.f, 0.f, 0.f, 0.f};
                    acc = __builtin_amdgcn_mfma_f32_16x16x32_bf16(A0, Bf[c4][0], acc, 0, 0, 0);
                    acc = __builtin_amdgcn_mfma_f32_16x16x32_bf16(A1, Bf[c4][1], acc, 0, 0, 0);
                    vmax[c4] = fmaxf(vmax[c4],
                               fmaxf(fmaxf(acc[0], acc[1]), fmaxf(acc[2], acc[3])));
                }
            }
            __syncthreads();
        }
#pragma unroll
        for (int c4 = 0; c4 < 4; ++c4) {
            vmax[c4] = fmaxf(vmax[c4], __shfl_xor(vmax[c4], 16, 64));
            vmax[c4] = fmaxf(vmax[c4], __shfl_xor(vmax[c4], 32, 64));
        }
        if (l < 16) {
#pragma unroll
            for (int c4 = 0; c4 < 4; ++c4) {
                int c = w*64 + c4*16 + l;
                featb[(size_t)b*4608 + 2048 + c] = f2bf(lrelu(vmax[c4] + lb2[c]));
            }
        }
    } else {
        // ===== KNN SELECT (block = batch b, quarter qt; 1024 pts) =====
        float* sd = (float*)smem;           // [64]
        int*   sn = (int*)(smem + 256);     // [64]
        int sblk = blk - 384;
        int b = sblk >> 2, qt = sblk & 3;
        const float4* pb4 = (const float4*)(gpc + ((size_t)b*4096 + qt*1024)*3);
        float qx = query[b*3+0], qy = query[b*3+1], qz = query[b*3+2];
        float sq = qx*qx + qy*qy + qz*qz;

        float4 v0 = pb4[t*3+0], v1 = pb4[t*3+1], v2 = pb4[t*3+2];
        float pxa[4] = {v0.x, v0.w, v1.z, v2.y};
        float pya[4] = {v0.y, v1.x, v1.w, v2.z};
        float pza[4] = {v0.z, v1.y, v2.x, v2.w};
        float d2[4];
#pragma unroll
        for (int j = 0; j < 4; ++j) {
            float sp = pxa[j]*pxa[j] + pya[j]*pya[j] + pza[j]*pza[j];
            d2[j] = sq + sp - 2.0f*(qx*pxa[j] + qy*pya[j] + qz*pza[j]);
        }
        int nbase = qt*1024 + t*4;

        unsigned avail = 0xFu;
        float myd = 0.f; int myn = 0;
        for (int r = 0; r < 16; ++r) {
            float bd = INFINITY; int bn = 0x7fffffff, bj = -1;
#pragma unroll
            for (int j = 0; j < 4; ++j) {
                float d = (avail & (1u << j)) ? d2[j] : INFINITY;
                if (d < bd) { bd = d; bn = nbase + j; bj = j; }
            }
            float wd = bd; int wn = bn;
#pragma unroll
            for (int off = 32; off; off >>= 1) {
                float od = __shfl_xor(wd, off, 64);
                int   on = __shfl_xor(wn, off, 64);
                if (od < wd || (od == wd && on < wn)) { wd = od; wn = on; }
            }
            if (wn == bn) avail &= ~(1u << bj);
            if (l == r) { myd = wd; myn = wn; }
        }
        if (l < 16) { sd[w*16 + l] = myd; sn[w*16 + l] = myn; }
        __syncthreads();
        if (w == 0) {
            float d = sd[l]; int n = sn[l];
            float myd2 = 0.f; int myn2 = 0;
            for (int r = 0; r < 16; ++r) {
                float wd = d; int wn = n;
#pragma unroll
                for (int off = 32; off; off >>= 1) {
                    float od = __shfl_xor(wd, off, 64);
                    int   on = __shfl_xor(wn, off, 64);
                    if (od < wd || (od == wd && on < wn)) { wd = od; wn = on; }
                }
                if (n == wn) d = INFINITY;
                if (l == r) { myd2 = wd; myn2 = wn; }
            }
            if (l < 16) {
                candd[(b*4 + qt)*16 + l] = myd2;
                candn[(b*4 + qt)*16 + l] = myn2;
            }
        }
    }
}

// ---------------------------------------------------------------------------
// Attention: merge 64 candidates -> top-16, then PointNet features +
// attention + pos-embed. Grid 128, block 256.
// ---------------------------------------------------------------------------
__global__ __launch_bounds__(256) void k_attn(
    const float* __restrict__ gpc, const float* __restrict__ query,
    const float* __restrict__ candd, const int* __restrict__ candn,
    const float* __restrict__ gw1, const float* __restrict__ gb1,
    const float* __restrict__ gw2, const float* __restrict__ gb2,
    const float* __restrict__ apw, const float* __restrict__ apb,
    const float* __restrict__ asw, const float* __restrict__ asb,
    const float* __restrict__ posw, const float* __restrict__ posb,
    const float* __restrict__ bng, const float* __restrict__ bnb,
    unsigned short* __restrict__ featb)
{
    __shared__ __align__(16) unsigned char smem[20992];
    float* h_all   = (float*)smem;            // [16][64]
    float* hqs     = (float*)(smem + 4096);   // [16][128]
    float* sc      = (float*)(smem + 12288);  // [16][128]
    float* knn_pos = (float*)(smem + 20480);  // [16][4]

    int b = blockIdx.x, t = threadIdx.x;
    int w = t >> 6, l = t & 63;
    float qx = query[b*3+0], qy = query[b*3+1], qz = query[b*3+2];

    if (w == 0) {   // merge 64 candidates (n unique across quarters)
        float d = candd[b*64 + l]; int n = candn[b*64 + l];
        int win_n = 0;
        for (int r = 0; r < 16; ++r) {
            float wd = d; int wn = n;
#pragma unroll
            for (int off = 32; off; off >>= 1) {
                float od = __shfl_xor(wd, off, 64);
                int   on = __shfl_xor(wn, off, 64);
                if (od < wd || (od == wd && on < wn)) { wd = od; wn = on; }
            }
            if (n == wn) d = INFINITY;
            if (l == r) win_n = wn;
        }
        if (l < 16) {
            const float* p = gpc + ((size_t)b*4096 + win_n)*3;
            knn_pos[l*4+0] = qx - p[0];
            knn_pos[l*4+1] = qy - p[1];
            knn_pos[l*4+2] = qz - p[2];
        }
    }
    __syncthreads();

    { // h for 16 neighbors
        int r = t >> 4, kk = (t & 15) * 4;
        float ppx = qx - knn_pos[r*4+0];
        float ppy = qy - knn_pos[r*4+1];
        float ppz = qz - knn_pos[r*4+2];
#pragma unroll
        for (int i = 0; i < 4; ++i) {
            int k = kk + i;
            h_all[r*64 + k] = lrelu(fmaf(ppx, gw1[k],
                               fmaf(ppy, gw1[64+k], fmaf(ppz, gw1[128+k], gb1[k]))));
        }
    }
    __syncthreads();
    { // hq = lrelu(h@gw2 + gb2) + (knn_pos@apw + apb)
        int r = t >> 4, c0 = (t & 15) * 8;
        float acc[8];
#pragma unroll
        for (int i = 0; i < 8; ++i) acc[i] = gb2[c0+i];
#pragma unroll 8
        for (int k = 0; k < 64; ++k) {
            float hv = h_all[r*64 + k];
            float4 wv0 = *(const float4*)(gw2 + k*128 + c0);
            float4 wv1 = *(const float4*)(gw2 + k*128 + c0 + 4);
            acc[0] = fmaf(hv, wv0.x, acc[0]); acc[1] = fmaf(hv, wv0.y, acc[1]);
            acc[2] = fmaf(hv, wv0.z, acc[2]); acc[3] = fmaf(hv, wv0.w, acc[3]);
            acc[4] = fmaf(hv, wv1.x, acc[4]); acc[5] = fmaf(hv, wv1.y, acc[5]);
            acc[6] = fmaf(hv, wv1.z, acc[6]); acc[7] = fmaf(hv, wv1.w, acc[7]);
        }
        float kx = knn_pos[r*4+0], ky = knn_pos[r*4+1], kz = knn_pos[r*4+2];
#pragma unroll
        for (int i = 0; i < 8; ++i) {
            int c = c0 + i;
            float pe = fmaf(kx, apw[c], fmaf(ky, apw[128+c], fmaf(kz, apw[256+c], apb[c])));
            acc[i] = lrelu(acc[i]) + pe;
        }
        *(float4*)(hqs + r*128 + c0)     = make_float4(acc[0], acc[1], acc[2], acc[3]);
        *(float4*)(hqs + r*128 + c0 + 4) = make_float4(acc[4], acc[5], acc[6], acc[7]);
    }
    __syncthreads();
    { // scores
        int r = t >> 4, c0 = (t & 15) * 8;
        float acc[8];
#pragma unroll
        for (int i = 0; i < 8; ++i) acc[i] = asb[c0+i];
#pragma unroll 8
        for (int k = 0; k < 128; ++k) {
            float hv = hqs[r*128 + k];
            float4 wv0 = *(const float4*)(asw + k*128 + c0);
            float4 wv1 = *(const float4*)(asw + k*128 + c0 + 4);
            acc[0] = fmaf(hv, wv0.x, acc[0]); acc[1] = fmaf(hv, wv0.y, acc[1]);
            acc[2] = fmaf(hv, wv0.z, acc[2]); acc[3] = fmaf(hv, wv0.w, acc[3]);
            acc[4] = fmaf(hv, wv1.x, acc[4]); acc[5] = fmaf(hv, wv1.y, acc[5]);
            acc[6] = fmaf(hv, wv1.z, acc[6]); acc[7] = fmaf(hv, wv1.w, acc[7]);
        }
        *(float4*)(sc + r*128 + c0)     = make_float4(acc[0], acc[1], acc[2], acc[3]);
        *(float4*)(sc + r*128 + c0 + 4) = make_float4(acc[4], acc[5], acc[6], acc[7]);
    }
    __syncthreads();
    if (t < 128) { // softmax + weighted sum
        int c = t;
        float s[16]; float mx = -INFINITY;
#pragma unroll
        for (int r = 0; r < 16; ++r) { s[r] = sc[r*128 + c]; mx = fmaxf(mx, s[r]); }
        float sum = 0.f;
#pragma unroll
        for (int r = 0; r < 16; ++r) { s[r] = expf(s[r] - mx); sum += s[r]; }
        float inv = 1.0f / sum;
        float qf = 0.f;
#pragma unroll
        for (int r = 0; r < 16; ++r) qf = fmaf(s[r]*inv, hqs[r*128 + c], qf);
        featb[(size_t)b*4608 + 2304 + c] = f2bf(qf);
    } else {       // position embedding (waves 2-3)
        int c = t - 128;
        float pv = fmaf(qx, posw[c], fmaf(qy, posw[128+c], fmaf(qz, posw[256+c], posb[c])));
        pv = lrelu(fmaf(bng[c], pv, bnb[c]));
        featb[(size_t)b*4608 + 2432 + c] = f2bf(pv);
    }
}

// ---------------------------------------------------------------------------
// Decoder layer 1: LDS-free register MFMA GEMM, B pre-transposed bf16.
// ---------------------------------------------------------------------------
__global__ __launch_bounds__(256) void k_dec1(
    const unsigned short* __restrict__ featb, const unsigned short* __restrict__ dw1T,
    float* __restrict__ partial)      // [18][128][512]
{
    int kc = blockIdx.x, mg = blockIdx.y, ng = blockIdx.z;
    int t = threadIdx.x, w = t >> 6, l = t & 63;
    int q = l >> 4;
    int n0 = ng*64 + w*16 + (l & 15);
    const unsigned short* brow = dw1T + (size_t)n0*4608;

    f32x4 acc[2] = {{0.f,0.f,0.f,0.f},{0.f,0.f,0.f,0.f}};
#pragma unroll
    for (int ks = 0; ks < 8; ++ks) {
        int ka = kc*256 + ks*32 + q*8;
        bf16x8 Bf = *(const bf16x8*)(brow + ka);
#pragma unroll
        for (int mi = 0; mi < 2; ++mi) {
            int row = mg*32 + mi*16 + (l & 15);
            bf16x8 Af = *(const bf16x8*)(featb + (size_t)row*4608 + ka);
            acc[mi] = __builtin_amdgcn_mfma_f32_16x16x32_bf16(Af, Bf, acc[mi], 0, 0, 0);
        }
    }
    float* pb = partial + (size_t)kc*65536;
#pragma unroll
    for (int mi = 0; mi < 2; ++mi) {
#pragma unroll
        for (int r = 0; r < 4; ++r) {
            int row = mg*32 + mi*16 + q*4 + r;
            pb[row*512 + n0] = acc[mi][r];
        }
    }
}

__global__ __launch_bounds__(512) void k_dec2(
    const float* __restrict__ partial, const float* __restrict__ b1,
    const float* __restrict__ w2, const float* __restrict__ b2,
    float* __restrict__ out)
{
    int b = blockIdx.x, t = threadIdx.x;
    float acc = b1[t];
#pragma unroll
    for (int kc = 0; kc < 18; ++kc)
        acc += partial[(size_t)kc*65536 + b*512 + t];
    float v = lrelu(acc) * w2[t];
#pragma unroll
    for (int off = 32; off; off >>= 1) v += __shfl_xor(v, off, 64);
    __shared__ float red[8];
    if ((t & 63) == 0) red[t >> 6] = v;
    __syncthreads();
    if (t == 0) {
        float s_ = 0.f;
#pragma unroll
        for (int i = 0; i < 8; ++i) s_ += red[i];
        out[b] = s_ + b2[0];
    }
}

extern "C" void kernel_launch(void* const* d_in, const int* in_sizes, int n_in,
                              void* d_out, int out_size, void* d_ws, size_t ws_size,
                              hipStream_t stream)
{
    const float* pc_voxel  = (const float*)d_in[0];
    const float* global_pc = (const float*)d_in[1];
    const float* local_pc  = (const float*)d_in[2];
    const float* query     = (const float*)d_in[3];
    const float* voxel     = (const float*)d_in[4];
    const float* ge_w1 = (const float*)d_in[5];
    const float* ge_b1 = (const float*)d_in[6];
    const float* ge_w2 = (const float*)d_in[7];
    const float* ge_b2 = (const float*)d_in[8];
    // d_in[9..10] = ge_w3/ge_b3: dead (global_c unused by decoder)
    const float* le_w1 = (const float*)d_in[11];
    const float* le_b1 = (const float*)d_in[12];
    const float* le_w2 = (const float*)d_in[13];
    const float* le_b2 = (const float*)d_in[14];
    const float* pos_w = (const float*)d_in[15];
    const float* pos_b = (const float*)d_in[16];
    const float* bn_g  = (const float*)d_in[17];
    const float* bn_b  = (const float*)d_in[18];
    const float* apw   = (const float*)d_in[19];
    const float* apb   = (const float*)d_in[20];
    const float* asw   = (const float*)d_in[21];
    const float* asb   = (const float*)d_in[22];
    const float* gw1 = (const float*)d_in[23];
    const float* gb1 = (const float*)d_in[24];
    const float* gw2 = (const float*)d_in[25];
    const float* gb2 = (const float*)d_in[26];
    const float* fw1 = (const float*)d_in[27];
    const float* fb1 = (const float*)d_in[28];
    const float* fw2 = (const float*)d_in[29];
    const float* fb2 = (const float*)d_in[30];
    const float* dw1 = (const float*)d_in[31];
    const float* db1 = (const float*)d_in[32];
    const float* dw2 = (const float*)d_in[33];
    const float* db2 = (const float*)d_in[34];

    unsigned short* featb = (unsigned short*)d_ws;                    //  1,179,648 B
    float* partial = (float*)((char*)d_ws + 1179648);                 //  4,718,592 B
    unsigned short* dw1T = (unsigned short*)((char*)d_ws + 5898240);  //  4,718,592 B
    unsigned short* w2T  = (unsigned short*)((char*)d_ws + 10616832); //     55,296 B
    float* candd = (float*)((char*)d_ws + 10672128);                  //     32,768 B
    int*   candn = (int*)((char*)d_ws + 10704896);                    //     32,768 B
    float* out = (float*)d_out;

    k_prep<<<577, 256, 0, stream>>>(dw1, gw2, fw2, dw1T, w2T);
    k_mega<<<896, 256, 0, stream>>>(pc_voxel, voxel, gw1, gb1, gb2, fw1, fb1, fb2,
                                    w2T, local_pc, le_w1, le_b1, le_w2, le_b2,
                                    global_pc, query, candd, candn, featb);
    k_attn<<<128, 256, 0, stream>>>(global_pc, query, candd, candn,
                                    ge_w1, ge_b1, ge_w2, ge_b2,
                                    apw, apb, asw, asb, pos_w, pos_b, bn_g, bn_b, featb);
    k_dec1<<<dim3(18, 4, 8), 256, 0, stream>>>(featb, dw1T, partial);
    k_dec2<<<128, 512, 0, stream>>>(partial, db1, dw2, db2, out);
}

// Round 7
// 188.811 us; speedup vs baseline: 1.2605x; 1.1569x over previous
//
#include <hip/hip_runtime.h>
#include <math.h>

#define LEAKY 0.2f
__device__ __forceinline__ float lrelu(float x){ return x >= 0.0f ? x : LEAKY*x; }

__device__ __forceinline__ unsigned short f2bf(float x){
    union { float f; unsigned u; } v; v.f = x;
    unsigned r = v.u + 0x7FFFu + ((v.u >> 16) & 1u);
    return (unsigned short)(r >> 16);
}
__device__ __forceinline__ unsigned pack2(float a, float b){
    return (unsigned)f2bf(a) | ((unsigned)f2bf(b) << 16);
}

typedef __attribute__((ext_vector_type(8))) short bf16x8;
typedef __attribute__((ext_vector_type(4))) float f32x4;

// ---------------------------------------------------------------------------
// Prep: blocks 0..575 transpose dec_w1 -> dw1T [512][4608] bf16;
// 576: w2T[branch][co32][kp27][ci16]; 577: gw2T [128n][64k]; 578: aswT [128n][128k].
// ---------------------------------------------------------------------------
__global__ __launch_bounds__(256) void k_prep(
    const float* __restrict__ dw1,
    const float* __restrict__ gvw2, const float* __restrict__ fvw2,
    const float* __restrict__ gw2, const float* __restrict__ asw,
    unsigned short* __restrict__ dw1T, unsigned short* __restrict__ w2T,
    unsigned short* __restrict__ gw2T, unsigned short* __restrict__ aswT)
{
    int blk = blockIdx.x, t = threadIdx.x;
    if (blk == 576) {
        for (int e = t; e < 27648; e += 256) {
            int branch = e / 13824, r = e - branch*13824;
            int co = r / 432, r2 = r - co*432;
            int kp = r2 >> 4, ci = r2 & 15;
            const float* src = branch ? fvw2 : gvw2;
            w2T[e] = f2bf(src[(kp*16 + ci)*32 + co]);
        }
        return;
    }
    if (blk == 577) {
        for (int e = t; e < 8192; e += 256) {
            int n = e >> 6, k = e & 63;
            gw2T[e] = f2bf(gw2[k*128 + n]);
        }
        return;
    }
    if (blk == 578) {
        for (int e = t; e < 16384; e += 256) {
            int n = e >> 7, k = e & 127;
            aswT[e] = f2bf(asw[k*128 + n]);
        }
        return;
    }
    __shared__ float s[64*65];
    int kt = blk % 72, nt = blk / 72;
    int k0 = kt*64, n0 = nt*64;
#pragma unroll
    for (int p = 0; p < 4; ++p) {
        int row = p*16 + (t >> 4);
        int col = (t & 15) * 4;
        float4 v = *(const float4*)(dw1 + (size_t)(k0 + row)*512 + n0 + col);
        s[row*65 + col]   = v.x; s[row*65 + col+1] = v.y;
        s[row*65 + col+2] = v.z; s[row*65 + col+3] = v.w;
    }
    __syncthreads();
    int nr = t >> 2, kseg = (t & 3) * 16;
    unsigned d[8];
#pragma unroll
    for (int i = 0; i < 8; ++i)
        d[i] = pack2(s[(kseg + 2*i)*65 + nr], s[(kseg + 2*i + 1)*65 + nr]);
    unsigned short* dst = dw1T + (size_t)(n0 + nr)*4608 + k0 + kseg;
    *(uint4*)dst       = make_uint4(d[0], d[1], d[2], d[3]);
    *(uint4*)(dst + 8) = make_uint4(d[4], d[5], d[6], d[7]);
}

// ---------------------------------------------------------------------------
// Mega: voxel (0..255) + local (256..383) + KNN+attention (384..511).
// ---------------------------------------------------------------------------
__global__ __launch_bounds__(256) void k_mega(
    const float* __restrict__ pcv, const float* __restrict__ vox,
    const float* __restrict__ gvw1, const float* __restrict__ gvb1,
    const float* __restrict__ gvb2,
    const float* __restrict__ fvw1, const float* __restrict__ fvb1,
    const float* __restrict__ fvb2,
    const unsigned short* __restrict__ w2T,
    const float* __restrict__ lpc,
    const float* __restrict__ lw1, const float* __restrict__ lb1,
    const float* __restrict__ lw2, const float* __restrict__ lb2,
    const float* __restrict__ gpc, const float* __restrict__ query,
    const float* __restrict__ gw1, const float* __restrict__ gb1,
    const float* __restrict__ gb2v,
    const unsigned short* __restrict__ gw2T, const unsigned short* __restrict__ aswT,
    const float* __restrict__ apw, const float* __restrict__ apb,
    const float* __restrict__ asb,
    const float* __restrict__ posw, const float* __restrict__ posb,
    const float* __restrict__ bng, const float* __restrict__ bnb,
    unsigned short* __restrict__ featb)
{
    __shared__ __align__(16) unsigned char smem[50176];
    int blk = blockIdx.x, t = threadIdx.x;
    int w = t >> 6, l = t & 63;

    if (blk < 256) {
        // ===== VOXEL =====
        float* s_in = (float*)smem;                            // [17][17][17]
        unsigned short* mid = (unsigned short*)(smem + 19664); // [9][9][9][16]
        int branch = blk >> 7, b = blk & 127;
        const float* in = (branch ? vox : pcv) + (size_t)b*4096;
        const float* w1 = branch ? fvw1 : gvw1;
        const float* b1 = branch ? fvb1 : gvb1;
        const float* b2 = branch ? fvb2 : gvb2;
        const unsigned short* w2t = w2T + branch*13824;

        for (int i = t; i < 4913; i += 256) s_in[i] = 0.f;
        for (int i = t; i < 5832; i += 256) ((unsigned*)mid)[i] = 0u;
        __syncthreads();
        for (int i = t; i < 4096; i += 256) {
            int id = i >> 8, ih = (i >> 4) & 15, iw = i & 15;
            s_in[id*289 + ih*17 + iw] = in[i];
        }
        __syncthreads();

        { // conv1 MFMA
            int co = l & 15, q = l >> 4;
            bf16x8 Bf;
            int toff[8];
#pragma unroll
            for (int j = 0; j < 8; ++j) {
                int k = q*8 + j;
                float wv = (k < 27) ? w1[k*16 + co] : 0.f;
                Bf[j] = (short)f2bf(wv);
                if (k < 27) {
                    int kd = k / 9, kh = (k / 3) % 3, kw = k % 3;
                    toff[j] = kd*289 + kh*17 + kw;
                } else toff[j] = -1;
            }
            float bias = b1[co];
#pragma unroll
            for (int mi8 = 0; mi8 < 8; ++mi8) {
                int sp = (w*8 + mi8)*16 + (l & 15);
                int base = (sp >> 6)*578 + (((sp >> 3) & 7))*34 + (sp & 7)*2;
                unsigned av[4];
#pragma unroll
                for (int jj = 0; jj < 4; ++jj) {
                    float e0 = (toff[2*jj]   >= 0) ? s_in[base + toff[2*jj]]   : 0.f;
                    float e1 = (toff[2*jj+1] >= 0) ? s_in[base + toff[2*jj+1]] : 0.f;
                    av[jj] = pack2(e0, e1);
                }
                bf16x8 Af;
                *(uint4*)&Af = make_uint4(av[0], av[1], av[2], av[3]);
                f32x4 acc = {0.f,0.f,0.f,0.f};
                acc = __builtin_amdgcn_mfma_f32_16x16x32_bf16(Af, Bf, acc, 0, 0, 0);
#pragma unroll
                for (int r = 0; r < 4; ++r) {
                    int osp = (w*8 + mi8)*16 + q*4 + r;
                    int od = osp >> 6, oh = (osp >> 3) & 7, ow = osp & 7;
                    mid[(od*81 + oh*9 + ow)*16 + co] = f2bf(lrelu(acc[r] + bias));
                }
            }
        }
        __syncthreads();

        { // conv2 MFMA
            int nw = w & 1, mbase = (w >> 1) * 2;
            int co = nw*16 + (l & 15);
            int q = l >> 4;
            int q2 = q >> 1, ci0 = (q & 1)*8;
            int sp0 = mbase*16 + (l & 15);
            int sp1 = sp0 + 16;
            int s0 = ((sp0 >> 4)*2)*81 + (((sp0 >> 2) & 3)*2)*9 + (sp0 & 3)*2;
            int s1 = ((sp1 >> 4)*2)*81 + (((sp1 >> 2) & 3)*2)*9 + (sp1 & 3)*2;
            f32x4 acc0 = {0.f,0.f,0.f,0.f}, acc1 = {0.f,0.f,0.f,0.f};
#pragma unroll
            for (int ks = 0; ks < 14; ++ks) {
                int kp = 2*ks + q2;
                bool ok = (kp < 27);
                int kpc = ok ? kp : 0;
                int kpoff = (kpc/9)*81 + ((kpc/3)%3)*9 + (kpc%3);
                bf16x8 A0 = *(const bf16x8*)(mid + (s0 + kpoff)*16 + ci0);
                bf16x8 A1 = *(const bf16x8*)(mid + (s1 + kpoff)*16 + ci0);
                bf16x8 Bf = *(const bf16x8*)(w2t + (co*27 + kpc)*16 + ci0);
                if (!ok) { A0 = bf16x8{0,0,0,0,0,0,0,0}; A1 = bf16x8{0,0,0,0,0,0,0,0}; }
                acc0 = __builtin_amdgcn_mfma_f32_16x16x32_bf16(A0, Bf, acc0, 0, 0, 0);
                acc1 = __builtin_amdgcn_mfma_f32_16x16x32_bf16(A1, Bf, acc1, 0, 0, 0);
            }
            float bias = b2[co];
            unsigned short* o = featb + (size_t)b*4608 + (branch ? 2560 : 0);
#pragma unroll
            for (int r = 0; r < 4; ++r) {
                int spa = mbase*16 + q*4 + r;
                o[co*64 + spa]      = f2bf(lrelu(acc0[r] + bias));
                o[co*64 + spa + 16] = f2bf(lrelu(acc1[r] + bias));
            }
        }
    } else if (blk < 384) {
        // ===== LOCAL ENCODER =====
        unsigned char* lds = smem;
        int b = blk - 256;
#pragma unroll
        for (int q = 0; q < 8; ++q) {
            float f0 = lw2[(q*8+0)*256 + t], f1 = lw2[(q*8+1)*256 + t];
            float f2 = lw2[(q*8+2)*256 + t], f3 = lw2[(q*8+3)*256 + t];
            float f4 = lw2[(q*8+4)*256 + t], f5 = lw2[(q*8+5)*256 + t];
            float f6 = lw2[(q*8+6)*256 + t], f7 = lw2[(q*8+7)*256 + t];
            uint4 u = make_uint4(pack2(f0,f1), pack2(f2,f3), pack2(f4,f5), pack2(f6,f7));
            *(uint4*)(lds + t*128 + ((q ^ (t & 7)) * 16)) = u;
        }
        __syncthreads();

        bf16x8 Bf[4][2];
#pragma unroll
        for (int c4 = 0; c4 < 4; ++c4) {
#pragma unroll
            for (int ks = 0; ks < 2; ++ks) {
                int c = w*64 + c4*16 + (l & 15);
                int chunk = ks*4 + (l >> 4);
                Bf[c4][ks] = *(const bf16x8*)(lds + c*128 + ((chunk ^ (c & 7)) * 16));
            }
        }
        __syncthreads();

        float vmax[4] = {-INFINITY, -INFINITY, -INFINITY, -INFINITY};
        const float* pcb = lpc + (size_t)b*1024*3;

        for (int p = 0; p < 4; ++p) {
            {
                const float* pp = pcb + (p*256 + t)*3;
                float x = pp[0], y = pp[1], z = pp[2];
#pragma unroll
                for (int q = 0; q < 8; ++q) {
                    float hv[8];
#pragma unroll
                    for (int i = 0; i < 8; ++i) {
                        int k = q*8 + i;
                        hv[i] = lrelu(fmaf(x, lw1[k], fmaf(y, lw1[64+k], fmaf(z, lw1[128+k], lb1[k]))));
                    }
                    uint4 u = make_uint4(pack2(hv[0],hv[1]), pack2(hv[2],hv[3]),
                                         pack2(hv[4],hv[5]), pack2(hv[6],hv[7]));
                    *(uint4*)(lds + t*128 + ((q ^ (t & 7)) * 16)) = u;
                }
            }
            __syncthreads();
#pragma unroll 4
            for (int g = 0; g < 16; ++g) {
                int row = g*16 + (l & 15);
                bf16x8 A0 = *(const bf16x8*)(lds + row*128 + ((((l>>4))     ^ (row & 7)) * 16));
                bf16x8 A1 = *(const bf16x8*)(lds + row*128 + (((4 + (l>>4)) ^ (row & 7)) * 16));
#pragma unroll
                for (int c4 = 0; c4 < 4; ++c4) {
                    f32x4 acc = {0.f, 0.f, 0.f, 0.f};
                    acc = __builtin_amdgcn_mfma_f32_16x16x32_bf16(A0, Bf[c4][0], acc, 0, 0, 0);
                    acc = __builtin_amdgcn_mfma_f32_16x16x32_bf16(A1, Bf[c4][1], acc, 0, 0, 0);
                    vmax[c4] = fmaxf(vmax[c4],
                               fmaxf(fmaxf(acc[0], acc[1]), fmaxf(acc[2], acc[3])));
                }
            }
            __syncthreads();
        }
#pragma unroll
        for (int c4 = 0; c4 < 4; ++c4) {
            vmax[c4] = fmaxf(vmax[c4], __shfl_xor(vmax[c4], 16, 64));
            vmax[c4] = fmaxf(vmax[c4], __shfl_xor(vmax[c4], 32, 64));
        }
        if (l < 16) {
#pragma unroll
            for (int c4 = 0; c4 < 4; ++c4) {
                int c = w*64 + c4*16 + l;
                featb[(size_t)b*4608 + 2048 + c] = f2bf(lrelu(vmax[c4] + lb2[c]));
            }
        }
    } else {
        // ===== KNN + MFMA ATTENTION (one block per batch) =====
        float* pts     = (float*)smem;            // [4096*3] f32, dies after merge
        float* knn_pos = (float*)(smem + 49152);  // [16][4]
        float* sd      = (float*)(smem + 49408);  // [64]
        int*   sn      = (int*)(smem + 49664);    // [64]
        // overlays (valid after selection):
        unsigned char* hb  = smem;                // bf16 [16][64] swizzled (2 KB)
        float* hqs = (float*)(smem + 4096);       // [16][128] f32
        unsigned char* hqb = smem + 12288;        // bf16 [16][128] swizzled (4 KB)
        float* scs = (float*)(smem + 16384);      // [16][128] f32

        int b = blk - 384;
        const float* pb = gpc + (size_t)b*4096*3;
#pragma unroll
        for (int i = 0; i < 12; ++i)
            ((uint4*)pts)[t + 256*i] = ((const uint4*)pb)[t + 256*i];

        float qx = query[b*3+0], qy = query[b*3+1], qz = query[b*3+2];
        float sq = qx*qx + qy*qy + qz*qz;
        __syncthreads();

        float px[16], py[16], pz[16], d2[16];
#pragma unroll
        for (int j = 0; j < 16; ++j) {
            int n = t + 256*j;
            px[j] = pts[n*3+0]; py[j] = pts[n*3+1]; pz[j] = pts[n*3+2];
        }
#pragma unroll
        for (int j = 0; j < 16; ++j) {
            float sp = px[j]*px[j] + py[j]*py[j] + pz[j]*pz[j];
            d2[j] = sq + sp - 2.0f*(qx*px[j] + qy*py[j] + qz*pz[j]);
        }

        unsigned avail = 0xFFFFu;
        float myd = 0.f; int myn = 0;
        for (int r = 0; r < 16; ++r) {
            float bd = INFINITY; int bj = -1;
#pragma unroll
            for (int j = 0; j < 16; ++j) {
                float d = (avail & (1u << j)) ? d2[j] : INFINITY;
                if (d < bd) { bd = d; bj = j; }
            }
            int bn = (bj >= 0) ? (t + 256*bj) : 0x7fffffff;
            float wd = bd; int wn = bn;
#pragma unroll
            for (int off = 32; off; off >>= 1) {
                float od = __shfl_xor(wd, off, 64);
                int   on = __shfl_xor(wn, off, 64);
                if (od < wd || (od == wd && on < wn)) { wd = od; wn = on; }
            }
            if (wn == bn) avail &= ~(1u << bj);
            if (l == r) { myd = wd; myn = wn; }
        }
        if (l < 16) { sd[w*16 + l] = myd; sn[w*16 + l] = myn; }
        __syncthreads();

        if (w == 0) {  // merge 64 -> top16, n unique -> exact removal
            float d = sd[l]; int n = sn[l];
            int win_n = 0;
            for (int r = 0; r < 16; ++r) {
                float wd = d; int wn = n;
#pragma unroll
                for (int off = 32; off; off >>= 1) {
                    float od = __shfl_xor(wd, off, 64);
                    int   on = __shfl_xor(wn, off, 64);
                    if (od < wd || (od == wd && on < wn)) { wd = od; wn = on; }
                }
                if (n == wn) d = INFINITY;
                if (l == r) win_n = wn;
            }
            if (l < 16) {
                knn_pos[l*4+0] = qx - pts[win_n*3+0];
                knn_pos[l*4+1] = qy - pts[win_n*3+1];
                knn_pos[l*4+2] = qz - pts[win_n*3+2];
            }
        }
        __syncthreads();   // pts dead

        { // h [16 nbr][64 ch] bf16 swizzled: thread = (r = t>>4, 4 ch)
            int r = t >> 4, kk = (t & 15) * 4;
            float ppx = qx - knn_pos[r*4+0];
            float ppy = qy - knn_pos[r*4+1];
            float ppz = qz - knn_pos[r*4+2];
            float hv[4];
#pragma unroll
            for (int i = 0; i < 4; ++i) {
                int k = kk + i;
                hv[i] = lrelu(fmaf(ppx, gw1[k], fmaf(ppy, gw1[64+k], fmaf(ppz, gw1[128+k], gb1[k]))));
            }
            int chunk = (t & 15) >> 1;
            int addr = r*128 + ((chunk ^ (r & 7)) * 16) + ((t & 15) & 1) * 8;
            *(uint2*)(hb + addr) = make_uint2(pack2(hv[0], hv[1]), pack2(hv[2], hv[3]));
        }
        __syncthreads();

        { // hq MFMA: [16x64]@[64x128]; wave handles n-tiles w*2, w*2+1
#pragma unroll
            for (int nn = 0; nn < 2; ++nn) {
                int nt = w*2 + nn;
                f32x4 acc = {0.f,0.f,0.f,0.f};
#pragma unroll
                for (int ks = 0; ks < 2; ++ks) {
                    int row = l & 15;
                    bf16x8 Af = *(const bf16x8*)(hb + row*128 + (((ks*4 + (l>>4)) ^ (row & 7)) * 16));
                    bf16x8 Bf = *(const bf16x8*)(gw2T + (nt*16 + (l & 15))*64 + ks*32 + (l>>4)*8);
                    acc = __builtin_amdgcn_mfma_f32_16x16x32_bf16(Af, Bf, acc, 0, 0, 0);
                }
                int c = nt*16 + (l & 15);
                float aw0 = apw[c], aw1 = apw[128+c], aw2 = apw[256+c], ab = apb[c], g2 = gb2v[c];
#pragma unroll
                for (int r = 0; r < 4; ++r) {
                    int rr = (l >> 4)*4 + r;
                    float kx = knn_pos[rr*4+0], ky = knn_pos[rr*4+1], kz = knn_pos[rr*4+2];
                    float pe = fmaf(kx, aw0, fmaf(ky, aw1, fmaf(kz, aw2, ab)));
                    float v = lrelu(acc[r] + g2) + pe;
                    hqs[rr*128 + c] = v;
                    int chunk = c >> 3;
                    *(unsigned short*)(hqb + rr*256 + ((chunk ^ (rr & 7)) * 16) + (c & 7)*2) = f2bf(v);
                }
            }
        }
        __syncthreads();

        { // sc MFMA: [16x128]@[128x128]
#pragma unroll
            for (int nn = 0; nn < 2; ++nn) {
                int nt = w*2 + nn;
                f32x4 acc = {0.f,0.f,0.f,0.f};
#pragma unroll
                for (int ks = 0; ks < 4; ++ks) {
                    int row = l & 15;
                    bf16x8 Af = *(const bf16x8*)(hqb + row*256 + (((ks*4 + (l>>4)) ^ (row & 7)) * 16));
                    bf16x8 Bf = *(const bf16x8*)(aswT + (nt*16 + (l & 15))*128 + ks*32 + (l>>4)*8);
                    acc = __builtin_amdgcn_mfma_f32_16x16x32_bf16(Af, Bf, acc, 0, 0, 0);
                }
                int c = nt*16 + (l & 15);
                float ab = asb[c];
#pragma unroll
                for (int r = 0; r < 4; ++r) {
                    int rr = (l >> 4)*4 + r;
                    scs[rr*128 + c] = acc[r] + ab;
                }
            }
        }
        __syncthreads();

        if (t < 128) { // softmax over 16 neighbors + weighted sum
            int c = t;
            float s[16]; float mx = -INFINITY;
#pragma unroll
            for (int r = 0; r < 16; ++r) { s[r] = scs[r*128 + c]; mx = fmaxf(mx, s[r]); }
            float sum = 0.f;
#pragma unroll
            for (int r = 0; r < 16; ++r) { s[r] = expf(s[r] - mx); sum += s[r]; }
            float inv = 1.0f / sum;
            float qf = 0.f;
#pragma unroll
            for (int r = 0; r < 16; ++r) qf = fmaf(s[r]*inv, hqs[r*128 + c], qf);
            featb[(size_t)b*4608 + 2304 + c] = f2bf(qf);
        } else {       // position embedding
            int c = t - 128;
            float pv = fmaf(qx, posw[c], fmaf(qy, posw[128+c], fmaf(qz, posw[256+c], posb[c])));
            pv = lrelu(fmaf(bng[c], pv, bnb[c]));
            featb[(size_t)b*4608 + 2432 + c] = f2bf(pv);
        }
    }
}

// ---------------------------------------------------------------------------
// Decoder layer 1: LDS-free register MFMA GEMM, B pre-transposed bf16.
// ---------------------------------------------------------------------------
__global__ __launch_bounds__(256) void k_dec1(
    const unsigned short* __restrict__ featb, const unsigned short* __restrict__ dw1T,
    float* __restrict__ partial)      // [18][128][512]
{
    int kc = blockIdx.x, mg = blockIdx.y, ng = blockIdx.z;
    int t = threadIdx.x, w = t >> 6, l = t & 63;
    int q = l >> 4;
    int n0 = ng*64 + w*16 + (l & 15);
    const unsigned short* brow = dw1T + (size_t)n0*4608;

    f32x4 acc[2] = {{0.f,0.f,0.f,0.f},{0.f,0.f,0.f,0.f}};
#pragma unroll
    for (int ks = 0; ks < 8; ++ks) {
        int ka = kc*256 + ks*32 + q*8;
        bf16x8 Bf = *(const bf16x8*)(brow + ka);
#pragma unroll
        for (int mi = 0; mi < 2; ++mi) {
            int row = mg*32 + mi*16 + (l & 15);
            bf16x8 Af = *(const bf16x8*)(featb + (size_t)row*4608 + ka);
            acc[mi] = __builtin_amdgcn_mfma_f32_16x16x32_bf16(Af, Bf, acc[mi], 0, 0, 0);
        }
    }
    float* pb = partial + (size_t)kc*65536;
#pragma unroll
    for (int mi = 0; mi < 2; ++mi) {
#pragma unroll
        for (int r = 0; r < 4; ++r) {
            int row = mg*32 + mi*16 + q*4 + r;
            pb[row*512 + n0] = acc[mi][r];
        }
    }
}

__global__ __launch_bounds__(512) void k_dec2(
    const float* __restrict__ partial, const float* __restrict__ b1,
    const float* __restrict__ w2, const float* __restrict__ b2,
    float* __restrict__ out)
{
    int b = blockIdx.x, t = threadIdx.x;
    float acc = b1[t];
#pragma unroll
    for (int kc = 0; kc < 18; ++kc)
        acc += partial[(size_t)kc*65536 + b*512 + t];
    float v = lrelu(acc) * w2[t];
#pragma unroll
    for (int off = 32; off; off >>= 1) v += __shfl_xor(v, off, 64);
    __shared__ float red[8];
    if ((t & 63) == 0) red[t >> 6] = v;
    __syncthreads();
    if (t == 0) {
        float s_ = 0.f;
#pragma unroll
        for (int i = 0; i < 8; ++i) s_ += red[i];
        out[b] = s_ + b2[0];
    }
}

extern "C" void kernel_launch(void* const* d_in, const int* in_sizes, int n_in,
                              void* d_out, int out_size, void* d_ws, size_t ws_size,
                              hipStream_t stream)
{
    const float* pc_voxel  = (const float*)d_in[0];
    const float* global_pc = (const float*)d_in[1];
    const float* local_pc  = (const float*)d_in[2];
    const float* query     = (const float*)d_in[3];
    const float* voxel     = (const float*)d_in[4];
    const float* ge_w1 = (const float*)d_in[5];
    const float* ge_b1 = (const float*)d_in[6];
    const float* ge_w2 = (const float*)d_in[7];
    const float* ge_b2 = (const float*)d_in[8];
    // d_in[9..10] = ge_w3/ge_b3: dead (global_c unused by decoder)
    const float* le_w1 = (const float*)d_in[11];
    const float* le_b1 = (const float*)d_in[12];
    const float* le_w2 = (const float*)d_in[13];
    const float* le_b2 = (const float*)d_in[14];
    const float* pos_w = (const float*)d_in[15];
    const float* pos_b = (const float*)d_in[16];
    const float* bn_g  = (const float*)d_in[17];
    const float* bn_b  = (const float*)d_in[18];
    const float* apw   = (const float*)d_in[19];
    const float* apb   = (const float*)d_in[20];
    const float* asw   = (const float*)d_in[21];
    const float* asb   = (const float*)d_in[22];
    const float* gw1 = (const float*)d_in[23];
    const float* gb1 = (const float*)d_in[24];
    const float* gw2 = (const float*)d_in[25];
    const float* gb2 = (const float*)d_in[26];
    const float* fw1 = (const float*)d_in[27];
    const float* fb1 = (const float*)d_in[28];
    const float* fw2 = (const float*)d_in[29];
    const float* fb2 = (const float*)d_in[30];
    const float* dw1 = (const float*)d_in[31];
    const float* db1 = (const float*)d_in[32];
    const float* dw2 = (const float*)d_in[33];
    const float* db2 = (const float*)d_in[34];

    unsigned short* featb = (unsigned short*)d_ws;                    //  1,179,648 B
    float* partial = (float*)((char*)d_ws + 1179648);                 //  4,718,592 B
    unsigned short* dw1T = (unsigned short*)((char*)d_ws + 5898240);  //  4,718,592 B
    unsigned short* w2T  = (unsigned short*)((char*)d_ws + 10616832); //     55,296 B
    unsigned short* gw2T = (unsigned short*)((char*)d_ws + 10672128); //     16,384 B
    unsigned short* aswT = (unsigned short*)((char*)d_ws + 10688512); //     32,768 B
    float* out = (float*)d_out;

    k_prep<<<579, 256, 0, stream>>>(dw1, gw2, fw2, ge_w2, asw, dw1T, w2T, gw2T, aswT);
    k_mega<<<512, 256, 0, stream>>>(pc_voxel, voxel, gw1, gb1, gb2, fw1, fb1, fb2,
                                    w2T, local_pc, le_w1, le_b1, le_w2, le_b2,
                                    global_pc, query, ge_w1, ge_b1, ge_b2,
                                    gw2T, aswT, apw, apb, asb,
                                    pos_w, pos_b, bn_g, bn_b, featb);
    k_dec1<<<dim3(18, 4, 8), 256, 0, stream>>>(featb, dw1T, partial);
    k_dec2<<<128, 512, 0, stream>>>(partial, db1, dw2, db2, out);
}